// Round 13
// baseline (1636.825 us; speedup 1.0000x reference)
//
#include <hip/hip_runtime.h>

typedef __attribute__((ext_vector_type(4))) float f32x4;
typedef __attribute__((ext_vector_type(8))) __bf16 bf16x8;

#define SEQ   257
#define NBATCH 32
#define DIMD  512
#define FFD   2048
#define NLYR  8
#define MROWS (NBATCH*SEQ)   /* 8224 */
#define MPAD  8320           /* 65*128 */
#define MSTEM 8192
#define KSTEM 4096
#define QKVD  1536

__device__ __forceinline__ unsigned short f2bf(float f) {
  unsigned int u = __float_as_uint(f);
  return (unsigned short)((u + 0x7FFFu + ((u >> 16) & 1u)) >> 16);
}
__device__ __forceinline__ float bf2f(unsigned short u) {
  return __uint_as_float(((unsigned int)u) << 16);
}
__device__ __forceinline__ float elu1(float x) { return x > 0.f ? x + 1.f : expf(x); }

__device__ __forceinline__ void gload16(const void* g, void* l) {
  __builtin_amdgcn_global_load_lds((__attribute__((address_space(1))) void*)g,
                                   (__attribute__((address_space(3))) void*)l, 16, 0, 0);
}

// ---------------------------------------------------------------- GEMM (2-phase, BK=64)
// C[M,N] = A[M,K](bf16) * BT[N,K](bf16) + bias.  BM=128, BN=64, waves 4x1, MW=2/NW=4;
// 48 KB dbuf LDS -> 3 blocks/CU.  For short-K GEMMs (K=512: QKV, O, FF1).
// EPI 0: fp32 out. EPI 1: gelu -> bf16 out. EPI 2: plain bf16 out.
// 1-D grid, by-fastest linearization + BIJECTIVE XCD-chunked swizzle.
// LDS XOR-swizzled (16B slot s of row r holds global slot s^(r&7)).
template<int EPI>
__global__ __launch_bounds__(256)
void gemm_bt(const unsigned short* __restrict__ A,
             const unsigned short* __restrict__ BT,
             const float* __restrict__ bias,
             void* __restrict__ Cout, int K, int Nn, int NBY) {
  constexpr int MW = 2;
  constexpr int NW = 4;
  constexpr int BM = 128;
  constexpr int BN = 64;
  __shared__ __align__(16) unsigned short sA[2][BM * 64];
  __shared__ __align__(16) unsigned short sB[2][BN * 64];
  const int tid = threadIdx.x;
  const int w = tid >> 6, l = tid & 63;
  const int nwg = gridDim.x;
  const int q = nwg >> 3, r = nwg & 7;
  const int xcd = blockIdx.x & 7, idx = blockIdx.x >> 3;
  const int wg = (xcd < r) ? (xcd * (q + 1) + idx) : (r * (q + 1) + (xcd - r) * q + idx);
  const int bx = wg / NBY, by = wg % NBY;
  const long tm = (long)bx * BM;
  const long tn = (long)by * BN;
  const int lr = l & 15, lg = l >> 4;
  const int lr7 = lr & 7;

  auto stage = [&](int buf, int t) {
    const long k0 = (long)t * 64;
#pragma unroll
    for (int j = 0; j < 4; ++j) {
      const int ch = j * 256 + tid;
      const int rr = ch >> 3, s = ch & 7;
      gload16(A + (tm + rr) * (long)K + k0 + ((s ^ (rr & 7)) * 8), sA[buf] + ch * 8);
    }
#pragma unroll
    for (int j = 0; j < 2; ++j) {
      const int ch = j * 256 + tid;
      const int rr = ch >> 3, s = ch & 7;
      gload16(BT + (tn + rr) * (long)K + k0 + ((s ^ (rr & 7)) * 8), sB[buf] + ch * 8);
    }
  };

  f32x4 acc[MW][NW];
#pragma unroll
  for (int m = 0; m < MW; ++m)
#pragma unroll
    for (int n = 0; n < NW; ++n) acc[m][n] = (f32x4){0.f, 0.f, 0.f, 0.f};

  const int nt = K >> 6;
  stage(0, 0);
  for (int t = 0; t < nt; ++t) {
    const int cur = t & 1;
    __syncthreads();
    if (t + 1 < nt) stage(cur ^ 1, t + 1);
#pragma unroll
    for (int kk = 0; kk < 2; ++kk) {
      const int sl = ((lg + kk * 4) ^ lr7) * 8;
      bf16x8 af[MW], bfr[NW];
#pragma unroll
      for (int m = 0; m < MW; ++m)
        af[m] = *(const bf16x8*)(sA[cur] + (w * MW * 16 + m * 16 + lr) * 64 + sl);
#pragma unroll
      for (int n = 0; n < NW; ++n)
        bfr[n] = *(const bf16x8*)(sB[cur] + (n * 16 + lr) * 64 + sl);
#pragma unroll
      for (int m = 0; m < MW; ++m)
#pragma unroll
        for (int n = 0; n < NW; ++n)
          acc[m][n] = __builtin_amdgcn_mfma_f32_16x16x32_bf16(af[m], bfr[n], acc[m][n], 0, 0, 0);
    }
  }
#pragma unroll
  for (int m = 0; m < MW; ++m) {
    const long gr0 = tm + w * MW * 16 + m * 16 + lg * 4;
#pragma unroll
    for (int n = 0; n < NW; ++n) {
      const long gc = tn + n * 16 + lr;
      const float bv = bias ? bias[gc] : 0.f;
#pragma unroll
      for (int j = 0; j < 4; ++j) {
        float v = acc[m][n][j] + bv;
        if (EPI == 0) {
          ((float*)Cout)[(gr0 + j) * (long)Nn + gc] = v;
        } else if (EPI == 1) {
          float g = 0.5f * v * (1.f + erff(v * 0.70710678118f));
          ((unsigned short*)Cout)[(gr0 + j) * (long)Nn + gc] = f2bf(g);
        } else {
          ((unsigned short*)Cout)[(gr0 + j) * (long)Nn + gc] = f2bf(v);
        }
      }
    }
  }
}

// ---------------------------------------------------------------- GEMM (3-buffer counted-vmcnt)
// Same geometry as gemm_bt but triple-buffered (72 KB LDS, 2 blocks/CU) with raw
// s_barrier + counted s_waitcnt vmcnt(N): prefetch stays 3 stages (2 full K-iters)
// deep, so the per-step load latency is fully hidden. 6 gload16/thread/stage ->
// vmcnt(12) waits exactly for stage t while t+1, t+2 stay in flight (T4, m135).
// Every ds_read is consumed by an MFMA before the trailing barrier (compiler
// lgkmcnt), so buffer reuse is race-free. For LONG-K GEMMs only (stem, FF2);
// at K=512 the 3-stage prologue dominates and 2-phase wins.
template<int EPI>
__global__ __launch_bounds__(256)
void gemm_bt_p3(const unsigned short* __restrict__ A,
                const unsigned short* __restrict__ BT,
                const float* __restrict__ bias,
                void* __restrict__ Cout, int K, int Nn, int NBY) {
  constexpr int MW = 2;
  constexpr int NW = 4;
  constexpr int BM = 128;
  constexpr int BN = 64;
  __shared__ __align__(16) unsigned short sA[3][BM * 64];
  __shared__ __align__(16) unsigned short sB[3][BN * 64];
  const int tid = threadIdx.x;
  const int w = tid >> 6, l = tid & 63;
  const int nwg = gridDim.x;
  const int q = nwg >> 3, r = nwg & 7;
  const int xcd = blockIdx.x & 7, idx = blockIdx.x >> 3;
  const int wg = (xcd < r) ? (xcd * (q + 1) + idx) : (r * (q + 1) + (xcd - r) * q + idx);
  const int bx = wg / NBY, by = wg % NBY;
  const long tm = (long)bx * BM;
  const long tn = (long)by * BN;
  const int lr = l & 15, lg = l >> 4;
  const int lr7 = lr & 7;

  auto stage = [&](int buf, int t) {
    const long k0 = (long)t * 64;
#pragma unroll
    for (int j = 0; j < 4; ++j) {
      const int ch = j * 256 + tid;
      const int rr = ch >> 3, s = ch & 7;
      gload16(A + (tm + rr) * (long)K + k0 + ((s ^ (rr & 7)) * 8), sA[buf] + ch * 8);
    }
#pragma unroll
    for (int j = 0; j < 2; ++j) {
      const int ch = j * 256 + tid;
      const int rr = ch >> 3, s = ch & 7;
      gload16(BT + (tn + rr) * (long)K + k0 + ((s ^ (rr & 7)) * 8), sB[buf] + ch * 8);
    }
  };

  f32x4 acc[MW][NW];
#pragma unroll
  for (int m = 0; m < MW; ++m)
#pragma unroll
    for (int n = 0; n < NW; ++n) acc[m][n] = (f32x4){0.f, 0.f, 0.f, 0.f};

  auto compute = [&](int buf) {
#pragma unroll
    for (int kk = 0; kk < 2; ++kk) {
      const int sl = ((lg + kk * 4) ^ lr7) * 8;
      bf16x8 af[MW], bfr[NW];
#pragma unroll
      for (int m = 0; m < MW; ++m)
        af[m] = *(const bf16x8*)(sA[buf] + (w * MW * 16 + m * 16 + lr) * 64 + sl);
#pragma unroll
      for (int n = 0; n < NW; ++n)
        bfr[n] = *(const bf16x8*)(sB[buf] + (n * 16 + lr) * 64 + sl);
#pragma unroll
      for (int m = 0; m < MW; ++m)
#pragma unroll
        for (int n = 0; n < NW; ++n)
          acc[m][n] = __builtin_amdgcn_mfma_f32_16x16x32_bf16(af[m], bfr[n], acc[m][n], 0, 0, 0);
    }
  };

  const int nt = K >> 6;   // callers guarantee nt >= 3
  stage(0, 0);
  stage(1, 1);
  stage(2, 2);
  int t = 0;
  for (; t < nt - 2; ++t) {
    asm volatile("s_waitcnt vmcnt(12)" ::: "memory");  // stage(t) landed; t+1,t+2 in flight
    __builtin_amdgcn_s_barrier();
    __builtin_amdgcn_sched_barrier(0);
    compute(t % 3);
    __builtin_amdgcn_s_barrier();                      // all waves done reading buf t%3
    if (t + 3 < nt) stage(t % 3, t + 3);               // overwrite just-consumed buffer
  }
  // t = nt-2: only stages nt-2, nt-1 outstanding (12 loads)
  asm volatile("s_waitcnt vmcnt(6)" ::: "memory");
  __builtin_amdgcn_s_barrier();
  __builtin_amdgcn_sched_barrier(0);
  compute((nt - 2) % 3);
  __builtin_amdgcn_s_barrier();
  // t = nt-1
  asm volatile("s_waitcnt vmcnt(0)" ::: "memory");
  __builtin_amdgcn_s_barrier();
  __builtin_amdgcn_sched_barrier(0);
  compute((nt - 1) % 3);

#pragma unroll
  for (int m = 0; m < MW; ++m) {
    const long gr0 = tm + w * MW * 16 + m * 16 + lg * 4;
#pragma unroll
    for (int n = 0; n < NW; ++n) {
      const long gc = tn + n * 16 + lr;
      const float bv = bias ? bias[gc] : 0.f;
#pragma unroll
      for (int j = 0; j < 4; ++j) {
        float v = acc[m][n][j] + bv;
        if (EPI == 0) {
          ((float*)Cout)[(gr0 + j) * (long)Nn + gc] = v;
        } else if (EPI == 1) {
          float g = 0.5f * v * (1.f + erff(v * 0.70710678118f));
          ((unsigned short*)Cout)[(gr0 + j) * (long)Nn + gc] = f2bf(g);
        } else {
          ((unsigned short*)Cout)[(gr0 + j) * (long)Nn + gc] = f2bf(v);
        }
      }
    }
  }
}

// ------------------------------------------------- batched transpose (fp32 -> bf16/fp32)
template<int OUT_BF>
__global__ void transpose_k(const float* __restrict__ src, void* __restrict__ dst,
                            int K, int N, long dstZ) {
  __shared__ float t[32][33];
  const long lz = blockIdx.z;
  const float* S = src + lz * (long)K * N;
  const long k0 = (long)blockIdx.x * 32, n0 = (long)blockIdx.y * 32;
  for (int i = threadIdx.y; i < 32; i += 8)
    t[i][threadIdx.x] = S[(k0 + i) * (long)N + n0 + threadIdx.x];
  __syncthreads();
  for (int i = threadIdx.y; i < 32; i += 8) {
    long o = lz * dstZ + (n0 + i) * (long)K + k0 + threadIdx.x;
    float val = t[threadIdx.x][i];
    if (OUT_BF) ((unsigned short*)dst)[o] = f2bf(val);
    else ((float*)dst)[o] = val;
  }
}

// ------------------------------------------------- W_eff: WeT[o, p*256+c] + fused stem bias
__global__ __launch_bounds__(256)
void weff_kernel(const float* __restrict__ embWT, const float* __restrict__ convW,
                 const float* __restrict__ emb_b, const float* __restrict__ conv_b,
                 unsigned short* __restrict__ WeT, float* __restrict__ bias2) {
  __shared__ float sc[8192];
  const int o = blockIdx.x;
  const float* C = convW + (long)o * 8192;
  for (int i = threadIdx.x; i < 8192; i += 256) sc[i] = C[i];
  __syncthreads();
  const int c = threadIdx.x;
  float acc[16];
#pragma unroll
  for (int p = 0; p < 16; ++p) acc[p] = 0.f;
  for (int d = 0; d < 512; ++d) {
    float ev = embWT[d * 256 + c];
#pragma unroll
    for (int p = 0; p < 16; ++p) acc[p] += ev * sc[d * 16 + p];
  }
#pragma unroll
  for (int p = 0; p < 16; ++p) WeT[(long)o * 4096 + p * 256 + c] = f2bf(acc[p]);
  float lb = 0.f;
  for (int d = c; d < 512; d += 256) {
    float s16 = 0.f;
#pragma unroll
    for (int p = 0; p < 16; ++p) s16 += sc[d * 16 + p];
    lb += emb_b[d] * s16;
  }
#pragma unroll
  for (int of = 1; of < 64; of <<= 1) lb += __shfl_xor(lb, of, 64);
  __shared__ float red[4];
  if ((threadIdx.x & 63) == 0) red[threadIdx.x >> 6] = lb;
  __syncthreads();
  if (threadIdx.x == 0) bias2[o] = red[0] + red[1] + red[2] + red[3] + conv_b[o];
}

// ------------------------------------------------- misc small kernels
__global__ void f32_to_bf16_k(const float* __restrict__ in, unsigned short* __restrict__ out, long n4) {
  long i = (long)blockIdx.x * blockDim.x + threadIdx.x;
  const long stride = (long)gridDim.x * blockDim.x;
  for (; i < n4; i += stride) {
    float4 v = ((const float4*)in)[i];
    ushort4 o; o.x = f2bf(v.x); o.y = f2bf(v.y); o.z = f2bf(v.z); o.w = f2bf(v.w);
    ((ushort4*)out)[i] = o;
  }
}

__global__ void rotary_k(float* __restrict__ cosT, float* __restrict__ sinT) {
  int idx = blockIdx.x * 256 + threadIdx.x;
  if (idx >= SEQ * 32) return;
  int s = idx >> 5, j = idx & 31;
  float inv = expf(-(float)(2 * j) * (1.f / 64.f) * 9.210340371976184f);
  float a = (float)s * inv;
  cosT[idx] = cosf(a);
  sinT[idx] = sinf(a);
}

__global__ void concat_bias_k(const float* __restrict__ bq, const float* __restrict__ bk,
                              const float* __restrict__ bv, float* __restrict__ bqkv) {
  int idx = blockIdx.x * 256 + threadIdx.x;
  if (idx >= NLYR * QKVD) return;
  int i = idx / QKVD, j = idx % QKVD;
  float v;
  if (j < 512) v = bq[i * 512 + j];
  else if (j < 1024) v = bk[i * 512 + j - 512];
  else v = bv[i * 512 + j - 1024];
  bqkv[idx] = v;
}

__global__ __launch_bounds__(256)
void masklen_k(const float* __restrict__ mask, float* __restrict__ mlen) {
  int n = blockIdx.x;
  float s = 0.f;
  for (int i = threadIdx.x; i < 4096; i += 256) s += mask[(long)n * 4096 + i];
#pragma unroll
  for (int of = 1; of < 64; of <<= 1) s += __shfl_xor(s, of, 64);
  __shared__ float red[4];
  if ((threadIdx.x & 63) == 0) red[threadIdx.x >> 6] = s;
  __syncthreads();
  if (threadIdx.x == 0) mlen[n] = ceilf((1.f + red[0] + red[1] + red[2] + red[3]) * (1.f / 16.f));
}

__global__ void assemble_x(const float* __restrict__ stem, const float* __restrict__ bias2,
                           const float* __restrict__ posemb, const float* __restrict__ cls,
                           float* __restrict__ Xf, unsigned short* __restrict__ Xbf) {
  long idx = (long)blockIdx.x * 256 + threadIdx.x;
  if (idx >= (long)MROWS * 128) return;
  long row = idx >> 7;
  int c4 = (int)(idx & 127) * 4;
  int n = (int)(row / SEQ), s = (int)(row % SEQ);
  float4 p = *(const float4*)(posemb + (long)s * DIMD + c4);
  float4 v;
  if (s == 0) {
    float4 cv = *(const float4*)(cls + c4);
    v.x = cv.x + p.x; v.y = cv.y + p.y; v.z = cv.z + p.z; v.w = cv.w + p.w;
  } else {
    float4 st = *(const float4*)(stem + ((long)(n * 256 + s - 1)) * DIMD + c4);
    float4 b2 = *(const float4*)(bias2 + c4);
    v.x = st.x + b2.x + p.x; v.y = st.y + b2.y + p.y; v.z = st.z + b2.z + p.z; v.w = st.w + b2.w + p.w;
  }
  *(float4*)(Xf + row * DIMD + c4) = v;
  ushort4 o; o.x = f2bf(v.x); o.y = f2bf(v.y); o.z = f2bf(v.z); o.w = f2bf(v.w);
  *(ushort4*)(Xbf + row * DIMD + c4) = o;
}

// ------------------------------------------------- fused MFMA linear attention
// One block per (n,h), 256 threads (4 waves). Unchanged from round 8.
__global__ __launch_bounds__(256)
void attn_fused_k(const unsigned short* __restrict__ QKV,
                  const float* __restrict__ cosT, const float* __restrict__ sinT,
                  const float* __restrict__ mlen, unsigned short* __restrict__ Obf) {
  const int n = blockIdx.x >> 3, h = blockIdx.x & 7;
  __shared__ __align__(16) unsigned short sKT[64 * 64];
  __shared__ __align__(16) unsigned short sVT[80 * 64];
  __shared__ __align__(16) unsigned short sKVT[80 * 64];
  __shared__ __align__(16) unsigned short sQ[64 * 64];
  const int t = threadIdx.x;
  const int w = t >> 6, ln = t & 63;
  const int lr = ln & 15, lg = ln >> 4;
  const int lr7 = lr & 7;
  const float mlen_n = mlen[n];

  {
    unsigned short val = (t < 16) ? (unsigned short)0x3F80 : (unsigned short)0;
    ushort4 iv; iv.x = val; iv.y = val; iv.z = val; iv.w = val;
    *(ushort4*)(sVT + 64 * 64 + t * 4) = iv;
  }

  f32x4 accA[5];
#pragma unroll
  for (int mt = 0; mt < 5; ++mt) accA[mt] = (f32x4){0.f, 0.f, 0.f, 0.f};

  for (int ch = 0; ch < 5; ++ch) {
#pragma unroll
    for (int pass = 0; pass < 4; ++pass) {
      const int slot = pass * 256 + t;
      const int sl_ = slot >> 4;
      const int j = slot & 15;
      const int c0 = 2 * j;
      const int srow = ch * 64 + sl_;
      float kr0 = 0.f, kr1 = 0.f, kr2 = 0.f, kr3 = 0.f;
      float v0 = 0.f, v1 = 0.f, v2 = 0.f, v3 = 0.f;
      if (srow < SEQ) {
        const unsigned short* Rw = QKV + ((long)(n * SEQ + srow)) * QKVD + h * 64;
        ushort2 ka = *(const ushort2*)(Rw + 512 + c0);
        ushort2 kb = *(const ushort2*)(Rw + 512 + c0 + 32);
        ushort2 va = *(const ushort2*)(Rw + 1024 + c0);
        ushort2 vb = *(const ushort2*)(Rw + 1024 + c0 + 32);
        float c0v = cosT[srow * 32 + c0], c1v = cosT[srow * 32 + c0 + 1];
        float s0v = sinT[srow * 32 + c0], s1v = sinT[srow * 32 + c0 + 1];
        float km = ((float)srow < mlen_n) ? 1.f : 0.f;
        float ka0 = bf2f(ka.x), ka1 = bf2f(ka.y), kb0 = bf2f(kb.x), kb1 = bf2f(kb.y);
        kr0 = elu1(ka0 * c0v - kb0 * s0v) * km;
        kr1 = elu1(ka1 * c1v - kb1 * s1v) * km;
        kr2 = elu1(kb0 * c0v + ka0 * s0v) * km;
        kr3 = elu1(kb1 * c1v + ka1 * s1v) * km;
        v0 = bf2f(va.x); v1 = bf2f(va.y); v2 = bf2f(vb.x); v3 = bf2f(vb.y);
      }
      const int sh = sl_ >> 3, slow = sl_ & 7;
      sKT[(c0)      * 64 + (((sh ^ ((c0)      & 7)) << 3) | slow)] = f2bf(kr0);
      sKT[(c0 + 1)  * 64 + (((sh ^ ((c0 + 1)  & 7)) << 3) | slow)] = f2bf(kr1);
      sKT[(c0 + 32) * 64 + (((sh ^ ((c0 + 32) & 7)) << 3) | slow)] = f2bf(kr2);
      sKT[(c0 + 33) * 64 + (((sh ^ ((c0 + 33) & 7)) << 3) | slow)] = f2bf(kr3);
      sVT[(c0)      * 64 + (((sh ^ ((c0)      & 7)) << 3) | slow)] = f2bf(v0);
      sVT[(c0 + 1)  * 64 + (((sh ^ ((c0 + 1)  & 7)) << 3) | slow)] = f2bf(v1);
      sVT[(c0 + 32) * 64 + (((sh ^ ((c0 + 32) & 7)) << 3) | slow)] = f2bf(v2);
      sVT[(c0 + 33) * 64 + (((sh ^ ((c0 + 33) & 7)) << 3) | slow)] = f2bf(v3);
    }
    __syncthreads();
#pragma unroll
    for (int kk = 0; kk < 2; ++kk) {
      const int sl = ((lg + kk * 4) ^ lr7) * 8;
      bf16x8 bk = *(const bf16x8*)(sKT + (w * 16 + lr) * 64 + sl);
#pragma unroll
      for (int mt = 0; mt < 5; ++mt) {
        bf16x8 av = *(const bf16x8*)(sVT + (mt * 16 + lr) * 64 + sl);
        accA[mt] = __builtin_amdgcn_mfma_f32_16x16x32_bf16(av, bk, accA[mt], 0, 0, 0);
      }
    }
    __syncthreads();
  }
  {
    const int d = w * 16 + lr;
    const int dh = d >> 3, dlow = d & 7;
#pragma unroll
    for (int mt = 0; mt < 5; ++mt) {
#pragma unroll
      for (int j = 0; j < 4; ++j) {
        const int m = mt * 16 + lg * 4 + j;
        sKVT[m * 64 + (((dh ^ (m & 7)) << 3) | dlow)] = f2bf(accA[mt][j]);
      }
    }
  }
  __syncthreads();

  for (int qt = 0; qt < 5; ++qt) {
#pragma unroll
    for (int pass = 0; pass < 4; ++pass) {
      const int slot = pass * 256 + t;
      const int ll = slot >> 4;
      const int j = slot & 15;
      const int c0 = 2 * j;
      int lq = qt * 64 + ll;
      const int lqc = (lq < SEQ) ? lq : (SEQ - 1);
      const unsigned short* Rw = QKV + ((long)(n * SEQ + lqc)) * QKVD + h * 64;
      ushort2 qa = *(const ushort2*)(Rw + c0);
      ushort2 qb = *(const ushort2*)(Rw + c0 + 32);
      float c0v = cosT[lqc * 32 + c0], c1v = cosT[lqc * 32 + c0 + 1];
      float s0v = sinT[lqc * 32 + c0], s1v = sinT[lqc * 32 + c0 + 1];
      float a0 = bf2f(qa.x), a1 = bf2f(qa.y), b0 = bf2f(qb.x), b1 = bf2f(qb.y);
      float q0 = elu1(a0 * c0v - b0 * s0v);
      float q1 = elu1(a1 * c1v - b1 * s1v);
      float q2 = elu1(b0 * c0v + a0 * s0v);
      float q3 = elu1(b1 * c1v + a1 * s1v);
      const int l7 = ll & 7;
      ushort2 p0; p0.x = f2bf(q0); p0.y = f2bf(q1);
      ushort2 p1; p1.x = f2bf(q2); p1.y = f2bf(q3);
      *(ushort2*)(sQ + ll * 64 + ((((c0 >> 3) ^ l7) << 3) | (c0 & 7))) = p0;
      *(ushort2*)(sQ + ll * 64 + (((((c0 + 32) >> 3) ^ l7) << 3) | (c0 & 7))) = p1;
    }
    __syncthreads();
    f32x4 accB[5];
#pragma unroll
    for (int nt = 0; nt < 5; ++nt) accB[nt] = (f32x4){0.f, 0.f, 0.f, 0.f};
#pragma unroll
    for (int kk = 0; kk < 2; ++kk) {
      const int sl = ((lg + kk * 4) ^ lr7) * 8;
      bf16x8 aq = *(const bf16x8*)(sQ + (w * 16 + lr) * 64 + sl);
#pragma unroll
      for (int nt = 0; nt < 5; ++nt) {
        bf16x8 bkv = *(const bf16x8*)(sKVT + (nt * 16 + lr) * 64 + sl);
        accB[nt] = __builtin_amdgcn_mfma_f32_16x16x32_bf16(aq, bkv, accB[nt], 0, 0, 0);
      }
    }
#pragma unroll
    for (int j = 0; j < 4; ++j) {
      float z = __shfl(accB[4][j], ln & 48, 64);
      float zr = 1.f / (z + 1e-6f);
      const int lq = qt * 64 + w * 16 + lg * 4 + j;
      if (lq < SEQ) {
        const long orow = ((long)(n * SEQ + lq)) * DIMD + h * 64;
#pragma unroll
        for (int nt = 0; nt < 4; ++nt)
          Obf[orow + nt * 16 + lr] = f2bf(accB[nt][j] * zr);
      }
    }
    __syncthreads();
  }
}

// y = LN(x + a) -> fp32 + bf16. A is bf16 (GEMM epilogues emit bf16).
__global__ __launch_bounds__(128)
void add_ln_k(const float* __restrict__ X, const unsigned short* __restrict__ A,
              const float* __restrict__ g, const float* __restrict__ b,
              float* __restrict__ Yf, unsigned short* __restrict__ Ybf) {
  int row = blockIdx.x, t = threadIdx.x;
  long base = (long)row * DIMD + t * 4;
  float4 xv = *(const float4*)(X + base);
  ushort4 au = *(const ushort4*)(A + base);
  float4 s;
  s.x = xv.x + bf2f(au.x); s.y = xv.y + bf2f(au.y);
  s.z = xv.z + bf2f(au.z); s.w = xv.w + bf2f(au.w);
  float sum = s.x + s.y + s.z + s.w;
  float sq = s.x * s.x + s.y * s.y + s.z * s.z + s.w * s.w;
#pragma unroll
  for (int of = 1; of < 64; of <<= 1) { sum += __shfl_xor(sum, of, 64); sq += __shfl_xor(sq, of, 64); }
  __shared__ float red[4];
  if ((t & 63) == 0) { red[(t >> 6) * 2] = sum; red[(t >> 6) * 2 + 1] = sq; }
  __syncthreads();
  sum = red[0] + red[2]; sq = red[1] + red[3];
  float mean = sum * (1.f / 512.f);
  float var = sq * (1.f / 512.f) - mean * mean;
  float rstd = rsqrtf(var + 1e-5f);
  float4 gv = *(const float4*)(g + t * 4);
  float4 bv = *(const float4*)(b + t * 4);
  float4 y;
  y.x = (s.x - mean) * rstd * gv.x + bv.x;
  y.y = (s.y - mean) * rstd * gv.y + bv.y;
  y.z = (s.z - mean) * rstd * gv.z + bv.z;
  y.w = (s.w - mean) * rstd * gv.w + bv.w;
  *(float4*)(Yf + base) = y;
  ushort4 o; o.x = f2bf(y.x); o.y = f2bf(y.y); o.z = f2bf(y.z); o.w = f2bf(y.w);
  *(ushort4*)(Ybf + base) = o;
}

// final LN + output heads. grid MROWS, block 128. out fp32: [32 global][8192 local]
__global__ __launch_bounds__(128)
void final_head_k(const float* __restrict__ X, const float* __restrict__ g, const float* __restrict__ b,
                  const float* __restrict__ condemb, const int* __restrict__ cond,
                  const float* __restrict__ outgW, const float* __restrict__ outgb,
                  const float* __restrict__ outlW, const float* __restrict__ outlb,
                  float* __restrict__ out) {
  int row = blockIdx.x, t = threadIdx.x;
  int n = row / SEQ, s = row % SEQ;
  long base = (long)row * DIMD + t * 4;
  float4 xv = *(const float4*)(X + base);
  float sum = xv.x + xv.y + xv.z + xv.w;
  float sq = xv.x * xv.x + xv.y * xv.y + xv.z * xv.z + xv.w * xv.w;
#pragma unroll
  for (int of = 1; of < 64; of <<= 1) { sum += __shfl_xor(sum, of, 64); sq += __shfl_xor(sq, of, 64); }
  __shared__ float red[4];
  if ((t & 63) == 0) { red[(t >> 6) * 2] = sum; red[(t >> 6) * 2 + 1] = sq; }
  __syncthreads();
  sum = red[0] + red[2]; sq = red[1] + red[3];
  float mean = sum * (1.f / 512.f);
  float var = sq * (1.f / 512.f) - mean * mean;
  float rstd = rsqrtf(var + 1e-5f);
  float4 gv = *(const float4*)(g + t * 4);
  float4 bv = *(const float4*)(b + t * 4);
  const float* wsel = (s == 0) ? outgW : outlW;
  const float* ce = condemb + (long)cond[n] * DIMD;
  float4 wv = *(const float4*)(wsel + t * 4);
  float4 cv = *(const float4*)(ce + t * 4);
  float l0 = (xv.x - mean) * rstd * gv.x + bv.x;
  float l1 = (xv.y - mean) * rstd * gv.y + bv.y;
  float l2 = (xv.z - mean) * rstd * gv.z + bv.z;
  float l3 = (xv.w - mean) * rstd * gv.w + bv.w;
  float pl = l0 * wv.x + l1 * wv.y + l2 * wv.z + l3 * wv.w;
  float pc = l0 * cv.x + l1 * cv.y + l2 * cv.z + l3 * cv.w;
#pragma unroll
  for (int of = 1; of < 64; of <<= 1) { pl += __shfl_xor(pl, of, 64); pc += __shfl_xor(pc, of, 64); }
  __shared__ float red2[4];
  if ((t & 63) == 0) { red2[(t >> 6) * 2] = pl; red2[(t >> 6) * 2 + 1] = pc; }
  __syncthreads();
  if (t == 0) {
    float res = red2[0] + red2[2] + red2[1] + red2[3] + ((s == 0) ? outgb[0] : outlb[0]);
    long oi = (s == 0) ? (long)n : (32 + (long)n * 256 + (s - 1));
    out[oi] = res;
  }
}

// ---------------------------------------------------------------- host
extern "C" void kernel_launch(void* const* d_in, const int* in_sizes, int n_in,
                              void* d_out, int out_size, void* d_ws, size_t ws_size,
                              hipStream_t stream) {
  const float* inputs    = (const float*)d_in[0];
  const float* input_mask= (const float*)d_in[1];
  const int*   cond      = (const int*)d_in[2];
  const float* emb_W     = (const float*)d_in[3];
  const float* emb_b     = (const float*)d_in[4];
  const float* conv_W    = (const float*)d_in[5];
  const float* conv_b    = (const float*)d_in[6];
  const float* pos_emb   = (const float*)d_in[7];
  const float* cls_token = (const float*)d_in[8];
  const float* Wq = (const float*)d_in[9];   const float* bq = (const float*)d_in[10];
  const float* Wk = (const float*)d_in[11];  const float* bk = (const float*)d_in[12];
  const float* Wv = (const float*)d_in[13];  const float* bv = (const float*)d_in[14];
  const float* Wo = (const float*)d_in[15];  const float* bo = (const float*)d_in[16];
  const float* ln1_g = (const float*)d_in[17]; const float* ln1_b = (const float*)d_in[18];
  const float* W1 = (const float*)d_in[19];  const float* b1 = (const float*)d_in[20];
  const float* W2 = (const float*)d_in[21];  const float* b2 = (const float*)d_in[22];
  const float* ln2_g = (const float*)d_in[23]; const float* ln2_b = (const float*)d_in[24];
  const float* normf_g = (const float*)d_in[25]; const float* normf_b = (const float*)d_in[26];
  const float* cond_emb = (const float*)d_in[27];
  const float* outg_W = (const float*)d_in[28]; const float* outg_b = (const float*)d_in[29];
  const float* outl_W = (const float*)d_in[30]; const float* outl_b = (const float*)d_in[31];

  char* ws = (char*)d_ws;
  size_t off = 0;
  auto alloc = [&](size_t bytes) -> char* {
    char* p = ws + off;
    off += (bytes + 255) & ~(size_t)255;
    return p;
  };
  unsigned short* WeT   = (unsigned short*)alloc((size_t)512 * 4096 * 2);
  float*          embWT = (float*)alloc((size_t)512 * 256 * 4);
  float*          bias2 = (float*)alloc(512 * 4);
  float*          cosT  = (float*)alloc(SEQ * 32 * 4);
  float*          sinT  = (float*)alloc(SEQ * 32 * 4);
  float*          mlen  = (float*)alloc(32 * 4);
  unsigned short* Wqkv  = (unsigned short*)alloc((size_t)NLYR * QKVD * 512 * 2);
  float*          bqkv  = (float*)alloc((size_t)NLYR * QKVD * 4);
  unsigned short* WoT = (unsigned short*)alloc((size_t)NLYR * 512 * 512 * 2);
  unsigned short* W1T = (unsigned short*)alloc((size_t)NLYR * 2048 * 512 * 2);
  unsigned short* W2T = (unsigned short*)alloc((size_t)NLYR * 512 * 2048 * 2);
  // in_bf (64 MB) only needed before the stem GEMM; tqkv_bf (25 MB) aliases it.
  char*           big  = alloc((size_t)MSTEM * KSTEM * 2);
  unsigned short* in_bf   = (unsigned short*)big;
  unsigned short* tqkv_bf = (unsigned short*)big;
  float*          x_f  = (float*)alloc((size_t)MPAD * DIMD * 4);
  unsigned short* x_bf = (unsigned short*)alloc((size_t)MPAD * DIMD * 2);
  float*          y_f  = (float*)alloc((size_t)MPAD * DIMD * 4);
  unsigned short* y_bf = (unsigned short*)alloc((size_t)MPAD * DIMD * 2);
  float*          t0   = (float*)alloc((size_t)MPAD * DIMD * 4);
  unsigned short* t0bf = (unsigned short*)alloc((size_t)MPAD * DIMD * 2);
  unsigned short* attn_bf = (unsigned short*)alloc((size_t)MPAD * DIMD * 2);
  unsigned short* h_bf = (unsigned short*)alloc((size_t)MPAD * FFD * 2);
  (void)ws_size; (void)in_sizes; (void)n_in; (void)out_size;

  dim3 tb(32, 8);
  // fused QKV weight: per layer rows [0..512)=Wq^T, [512..1024)=Wk^T, [1024..1536)=Wv^T
  transpose_k<1><<<dim3(16, 16, 8), tb, 0, stream>>>(Wq, Wqkv, 512, 512, (long)QKVD * 512);
  transpose_k<1><<<dim3(16, 16, 8), tb, 0, stream>>>(Wk, Wqkv + (size_t)512 * 512, 512, 512, (long)QKVD * 512);
  transpose_k<1><<<dim3(16, 16, 8), tb, 0, stream>>>(Wv, Wqkv + (size_t)1024 * 512, 512, 512, (long)QKVD * 512);
  transpose_k<1><<<dim3(16, 16, 8), tb, 0, stream>>>(Wo, WoT, 512, 512, (long)512 * 512);
  transpose_k<1><<<dim3(16, 64, 8), tb, 0, stream>>>(W1, W1T, 512, 2048, (long)512 * 2048);
  transpose_k<1><<<dim3(64, 16, 8), tb, 0, stream>>>(W2, W2T, 2048, 512, (long)2048 * 512);
  transpose_k<0><<<dim3(8, 16, 1), tb, 0, stream>>>(emb_W, embWT, 256, 512, 0);
  concat_bias_k<<<(NLYR * QKVD + 255) / 256, 256, 0, stream>>>(bq, bk, bv, bqkv);
  weff_kernel<<<512, 256, 0, stream>>>(embWT, conv_W, emb_b, conv_b, WeT, bias2);
  f32_to_bf16_k<<<4096, 256, 0, stream>>>(inputs, in_bf, (long)MSTEM * KSTEM / 4);
  rotary_k<<<(SEQ * 32 + 255) / 256, 256, 0, stream>>>(cosT, sinT);
  masklen_k<<<32, 256, 0, stream>>>(input_mask, mlen);

  // stem GEMM: (8192 x 4096) @ (4096 x 512) -> t0 fp32  [pipelined, nt=64, grid 512]
  gemm_bt_p3<0><<<512, 256, 0, stream>>>(in_bf, WeT, nullptr, t0, KSTEM, DIMD, 8);
  assemble_x<<<(MROWS * 128 + 255) / 256, 256, 0, stream>>>(t0, bias2, pos_emb, cls_token, x_f, x_bf);

  for (int i = 0; i < NLYR; ++i) {
    const unsigned short* wqkv = Wqkv + (size_t)i * QKVD * 512;
    const unsigned short* wo = WoT + (size_t)i * 512 * 512;
    const unsigned short* w1 = W1T + (size_t)i * 2048 * 512;
    const unsigned short* w2 = W2T + (size_t)i * 512 * 2048;
    // fused QKV -> bf16  [2-phase, grid 65x24 = 1560]
    gemm_bt<2><<<65 * 24, 256, 0, stream>>>(x_bf, wqkv, bqkv + i * QKVD, tqkv_bf, 512, QKVD, 24);
    attn_fused_k<<<256, 256, 0, stream>>>(tqkv_bf, cosT, sinT, mlen, attn_bf);
    // O-proj -> bf16  [2-phase, grid 65x8 = 520]
    gemm_bt<2><<<65 * 8, 256, 0, stream>>>(attn_bf, wo, bo + i * 512, t0bf, 512, 512, 8);
    add_ln_k<<<MROWS, 128, 0, stream>>>(x_f, t0bf, ln1_g + i * 512, ln1_b + i * 512, y_f, y_bf);
    // FF1 (gelu) -> bf16  [2-phase, grid 65x32 = 2080]
    gemm_bt<1><<<65 * 32, 256, 0, stream>>>(y_bf, w1, b1 + i * 2048, h_bf, 512, 2048, 32);
    // FF2 -> bf16  [pipelined, nt=32, grid 65x8 = 520]
    gemm_bt_p3<2><<<65 * 8, 256, 0, stream>>>(h_bf, w2, b2 + i * 512, t0bf, 2048, 512, 8);
    add_ln_k<<<MROWS, 128, 0, stream>>>(y_f, t0bf, ln2_g + i * 512, ln2_b + i * 512, x_f, x_bf);
  }
  final_head_k<<<MROWS, 128, 0, stream>>>(x_f, normf_g, normf_b, cond_emb, cond,
                                          outg_W, outg_b, outl_W, outl_b, (float*)d_out);
}

// Round 14
// 1492.721 us; speedup vs baseline: 1.0965x; 1.0965x over previous
//
#include <hip/hip_runtime.h>

typedef __attribute__((ext_vector_type(4))) float f32x4;
typedef __attribute__((ext_vector_type(8))) __bf16 bf16x8;

#define SEQ   257
#define NBATCH 32
#define DIMD  512
#define FFD   2048
#define NLYR  8
#define MROWS (NBATCH*SEQ)   /* 8224 */
#define MPAD  8320           /* 65*128 */
#define MSTEM 8192
#define KSTEM 4096
#define QKVD  1536

__device__ __forceinline__ unsigned short f2bf(float f) {
  unsigned int u = __float_as_uint(f);
  return (unsigned short)((u + 0x7FFFu + ((u >> 16) & 1u)) >> 16);
}
__device__ __forceinline__ float bf2f(unsigned short u) {
  return __uint_as_float(((unsigned int)u) << 16);
}
__device__ __forceinline__ float elu1(float x) { return x > 0.f ? x + 1.f : expf(x); }

__device__ __forceinline__ void gload16(const void* g, void* l) {
  __builtin_amdgcn_global_load_lds((__attribute__((address_space(1))) void*)g,
                                   (__attribute__((address_space(3))) void*)l, 16, 0, 0);
}

// ---------------------------------------------------------------- GEMM (2-phase, BK=64)
// C[M,N] = A[M,K](bf16) * BT[N,K](bf16) + bias.  BM=128, BN=64, waves 4x1, MW=2/NW=4;
// 48 KB dbuf LDS -> 3 blocks/CU.  Local optimum across 4 schedule probes:
//  - 128x128 tile (2 blk/CU): -100 us  (r10)
//  - BK=32 (5 blk/CU, 2x syncs): -84 us (r12)
//  - 3-buffer counted-vmcnt: -146 us (r13)
// EPI 0: fp32 out. EPI 1: gelu -> bf16 out. EPI 2: plain bf16 out.
// 1-D grid, by-fastest linearization + BIJECTIVE XCD-chunked swizzle.
// LDS XOR-swizzled (16B slot s of row r holds global slot s^(r&7)).
template<int EPI>
__global__ __launch_bounds__(256)
void gemm_bt(const unsigned short* __restrict__ A,
             const unsigned short* __restrict__ BT,
             const float* __restrict__ bias,
             void* __restrict__ Cout, int K, int Nn, int NBY) {
  constexpr int MW = 2;
  constexpr int NW = 4;
  constexpr int BM = 128;
  constexpr int BN = 64;
  __shared__ __align__(16) unsigned short sA[2][BM * 64];
  __shared__ __align__(16) unsigned short sB[2][BN * 64];
  const int tid = threadIdx.x;
  const int w = tid >> 6, l = tid & 63;
  const int nwg = gridDim.x;
  const int q = nwg >> 3, r = nwg & 7;
  const int xcd = blockIdx.x & 7, idx = blockIdx.x >> 3;
  const int wg = (xcd < r) ? (xcd * (q + 1) + idx) : (r * (q + 1) + (xcd - r) * q + idx);
  const int bx = wg / NBY, by = wg % NBY;
  const long tm = (long)bx * BM;
  const long tn = (long)by * BN;
  const int lr = l & 15, lg = l >> 4;
  const int lr7 = lr & 7;

  auto stage = [&](int buf, int t) {
    const long k0 = (long)t * 64;
#pragma unroll
    for (int j = 0; j < 4; ++j) {
      const int ch = j * 256 + tid;
      const int rr = ch >> 3, s = ch & 7;
      gload16(A + (tm + rr) * (long)K + k0 + ((s ^ (rr & 7)) * 8), sA[buf] + ch * 8);
    }
#pragma unroll
    for (int j = 0; j < 2; ++j) {
      const int ch = j * 256 + tid;
      const int rr = ch >> 3, s = ch & 7;
      gload16(BT + (tn + rr) * (long)K + k0 + ((s ^ (rr & 7)) * 8), sB[buf] + ch * 8);
    }
  };

  f32x4 acc[MW][NW];
#pragma unroll
  for (int m = 0; m < MW; ++m)
#pragma unroll
    for (int n = 0; n < NW; ++n) acc[m][n] = (f32x4){0.f, 0.f, 0.f, 0.f};

  const int nt = K >> 6;
  stage(0, 0);
  for (int t = 0; t < nt; ++t) {
    const int cur = t & 1;
    __syncthreads();
    if (t + 1 < nt) stage(cur ^ 1, t + 1);
#pragma unroll
    for (int kk = 0; kk < 2; ++kk) {
      const int sl = ((lg + kk * 4) ^ lr7) * 8;
      bf16x8 af[MW], bfr[NW];
#pragma unroll
      for (int m = 0; m < MW; ++m)
        af[m] = *(const bf16x8*)(sA[cur] + (w * MW * 16 + m * 16 + lr) * 64 + sl);
#pragma unroll
      for (int n = 0; n < NW; ++n)
        bfr[n] = *(const bf16x8*)(sB[cur] + (n * 16 + lr) * 64 + sl);
#pragma unroll
      for (int m = 0; m < MW; ++m)
#pragma unroll
        for (int n = 0; n < NW; ++n)
          acc[m][n] = __builtin_amdgcn_mfma_f32_16x16x32_bf16(af[m], bfr[n], acc[m][n], 0, 0, 0);
    }
  }
#pragma unroll
  for (int m = 0; m < MW; ++m) {
    const long gr0 = tm + w * MW * 16 + m * 16 + lg * 4;
#pragma unroll
    for (int n = 0; n < NW; ++n) {
      const long gc = tn + n * 16 + lr;
      const float bv = bias ? bias[gc] : 0.f;
#pragma unroll
      for (int j = 0; j < 4; ++j) {
        float v = acc[m][n][j] + bv;
        if (EPI == 0) {
          ((float*)Cout)[(gr0 + j) * (long)Nn + gc] = v;
        } else if (EPI == 1) {
          float g = 0.5f * v * (1.f + erff(v * 0.70710678118f));
          ((unsigned short*)Cout)[(gr0 + j) * (long)Nn + gc] = f2bf(g);
        } else {
          ((unsigned short*)Cout)[(gr0 + j) * (long)Nn + gc] = f2bf(v);
        }
      }
    }
  }
}

// ------------------------------------------------- batched transpose (fp32 -> bf16/fp32)
template<int OUT_BF>
__global__ void transpose_k(const float* __restrict__ src, void* __restrict__ dst,
                            int K, int N, long dstZ) {
  __shared__ float t[32][33];
  const long lz = blockIdx.z;
  const float* S = src + lz * (long)K * N;
  const long k0 = (long)blockIdx.x * 32, n0 = (long)blockIdx.y * 32;
  for (int i = threadIdx.y; i < 32; i += 8)
    t[i][threadIdx.x] = S[(k0 + i) * (long)N + n0 + threadIdx.x];
  __syncthreads();
  for (int i = threadIdx.y; i < 32; i += 8) {
    long o = lz * dstZ + (n0 + i) * (long)K + k0 + threadIdx.x;
    float val = t[threadIdx.x][i];
    if (OUT_BF) ((unsigned short*)dst)[o] = f2bf(val);
    else ((float*)dst)[o] = val;
  }
}

// ------------------------------------------------- W_eff: WeT[o, p*256+c] + fused stem bias
__global__ __launch_bounds__(256)
void weff_kernel(const float* __restrict__ embWT, const float* __restrict__ convW,
                 const float* __restrict__ emb_b, const float* __restrict__ conv_b,
                 unsigned short* __restrict__ WeT, float* __restrict__ bias2) {
  __shared__ float sc[8192];
  const int o = blockIdx.x;
  const float* C = convW + (long)o * 8192;
  for (int i = threadIdx.x; i < 8192; i += 256) sc[i] = C[i];
  __syncthreads();
  const int c = threadIdx.x;
  float acc[16];
#pragma unroll
  for (int p = 0; p < 16; ++p) acc[p] = 0.f;
  for (int d = 0; d < 512; ++d) {
    float ev = embWT[d * 256 + c];
#pragma unroll
    for (int p = 0; p < 16; ++p) acc[p] += ev * sc[d * 16 + p];
  }
#pragma unroll
  for (int p = 0; p < 16; ++p) WeT[(long)o * 4096 + p * 256 + c] = f2bf(acc[p]);
  float lb = 0.f;
  for (int d = c; d < 512; d += 256) {
    float s16 = 0.f;
#pragma unroll
    for (int p = 0; p < 16; ++p) s16 += sc[d * 16 + p];
    lb += emb_b[d] * s16;
  }
#pragma unroll
  for (int of = 1; of < 64; of <<= 1) lb += __shfl_xor(lb, of, 64);
  __shared__ float red[4];
  if ((threadIdx.x & 63) == 0) red[threadIdx.x >> 6] = lb;
  __syncthreads();
  if (threadIdx.x == 0) bias2[o] = red[0] + red[1] + red[2] + red[3] + conv_b[o];
}

// ------------------------------------------------- misc small kernels
__global__ void f32_to_bf16_k(const float* __restrict__ in, unsigned short* __restrict__ out, long n4) {
  long i = (long)blockIdx.x * blockDim.x + threadIdx.x;
  const long stride = (long)gridDim.x * blockDim.x;
  for (; i < n4; i += stride) {
    float4 v = ((const float4*)in)[i];
    ushort4 o; o.x = f2bf(v.x); o.y = f2bf(v.y); o.z = f2bf(v.z); o.w = f2bf(v.w);
    ((ushort4*)out)[i] = o;
  }
}

__global__ void rotary_k(float* __restrict__ cosT, float* __restrict__ sinT) {
  int idx = blockIdx.x * 256 + threadIdx.x;
  if (idx >= SEQ * 32) return;
  int s = idx >> 5, j = idx & 31;
  float inv = expf(-(float)(2 * j) * (1.f / 64.f) * 9.210340371976184f);
  float a = (float)s * inv;
  cosT[idx] = cosf(a);
  sinT[idx] = sinf(a);
}

__global__ void concat_bias_k(const float* __restrict__ bq, const float* __restrict__ bk,
                              const float* __restrict__ bv, float* __restrict__ bqkv) {
  int idx = blockIdx.x * 256 + threadIdx.x;
  if (idx >= NLYR * QKVD) return;
  int i = idx / QKVD, j = idx % QKVD;
  float v;
  if (j < 512) v = bq[i * 512 + j];
  else if (j < 1024) v = bk[i * 512 + j - 512];
  else v = bv[i * 512 + j - 1024];
  bqkv[idx] = v;
}

__global__ __launch_bounds__(256)
void masklen_k(const float* __restrict__ mask, float* __restrict__ mlen) {
  int n = blockIdx.x;
  float s = 0.f;
  for (int i = threadIdx.x; i < 4096; i += 256) s += mask[(long)n * 4096 + i];
#pragma unroll
  for (int of = 1; of < 64; of <<= 1) s += __shfl_xor(s, of, 64);
  __shared__ float red[4];
  if ((threadIdx.x & 63) == 0) red[threadIdx.x >> 6] = s;
  __syncthreads();
  if (threadIdx.x == 0) mlen[n] = ceilf((1.f + red[0] + red[1] + red[2] + red[3]) * (1.f / 16.f));
}

__global__ void assemble_x(const float* __restrict__ stem, const float* __restrict__ bias2,
                           const float* __restrict__ posemb, const float* __restrict__ cls,
                           float* __restrict__ Xf, unsigned short* __restrict__ Xbf) {
  long idx = (long)blockIdx.x * 256 + threadIdx.x;
  if (idx >= (long)MROWS * 128) return;
  long row = idx >> 7;
  int c4 = (int)(idx & 127) * 4;
  int n = (int)(row / SEQ), s = (int)(row % SEQ);
  float4 p = *(const float4*)(posemb + (long)s * DIMD + c4);
  float4 v;
  if (s == 0) {
    float4 cv = *(const float4*)(cls + c4);
    v.x = cv.x + p.x; v.y = cv.y + p.y; v.z = cv.z + p.z; v.w = cv.w + p.w;
  } else {
    float4 st = *(const float4*)(stem + ((long)(n * 256 + s - 1)) * DIMD + c4);
    float4 b2 = *(const float4*)(bias2 + c4);
    v.x = st.x + b2.x + p.x; v.y = st.y + b2.y + p.y; v.z = st.z + b2.z + p.z; v.w = st.w + b2.w + p.w;
  }
  *(float4*)(Xf + row * DIMD + c4) = v;
  ushort4 o; o.x = f2bf(v.x); o.y = f2bf(v.y); o.z = f2bf(v.z); o.w = f2bf(v.w);
  *(ushort4*)(Xbf + row * DIMD + c4) = o;
}

// ------------------------------------------------- fused MFMA linear attention
// One block per (n,h), 256 threads (4 waves). Round-8 structure + T5 setprio
// around MFMA clusters (attn-positive per m191; independent blocks at diverse
// phases = the regime where scheduler arbitration pays).
__global__ __launch_bounds__(256)
void attn_fused_k(const unsigned short* __restrict__ QKV,
                  const float* __restrict__ cosT, const float* __restrict__ sinT,
                  const float* __restrict__ mlen, unsigned short* __restrict__ Obf) {
  const int n = blockIdx.x >> 3, h = blockIdx.x & 7;
  __shared__ __align__(16) unsigned short sKT[64 * 64];
  __shared__ __align__(16) unsigned short sVT[80 * 64];
  __shared__ __align__(16) unsigned short sKVT[80 * 64];
  __shared__ __align__(16) unsigned short sQ[64 * 64];
  const int t = threadIdx.x;
  const int w = t >> 6, ln = t & 63;
  const int lr = ln & 15, lg = ln >> 4;
  const int lr7 = lr & 7;
  const float mlen_n = mlen[n];

  {
    unsigned short val = (t < 16) ? (unsigned short)0x3F80 : (unsigned short)0;
    ushort4 iv; iv.x = val; iv.y = val; iv.z = val; iv.w = val;
    *(ushort4*)(sVT + 64 * 64 + t * 4) = iv;
  }

  f32x4 accA[5];
#pragma unroll
  for (int mt = 0; mt < 5; ++mt) accA[mt] = (f32x4){0.f, 0.f, 0.f, 0.f};

  for (int ch = 0; ch < 5; ++ch) {
#pragma unroll
    for (int pass = 0; pass < 4; ++pass) {
      const int slot = pass * 256 + t;
      const int sl_ = slot >> 4;
      const int j = slot & 15;
      const int c0 = 2 * j;
      const int srow = ch * 64 + sl_;
      float kr0 = 0.f, kr1 = 0.f, kr2 = 0.f, kr3 = 0.f;
      float v0 = 0.f, v1 = 0.f, v2 = 0.f, v3 = 0.f;
      if (srow < SEQ) {
        const unsigned short* Rw = QKV + ((long)(n * SEQ + srow)) * QKVD + h * 64;
        ushort2 ka = *(const ushort2*)(Rw + 512 + c0);
        ushort2 kb = *(const ushort2*)(Rw + 512 + c0 + 32);
        ushort2 va = *(const ushort2*)(Rw + 1024 + c0);
        ushort2 vb = *(const ushort2*)(Rw + 1024 + c0 + 32);
        float c0v = cosT[srow * 32 + c0], c1v = cosT[srow * 32 + c0 + 1];
        float s0v = sinT[srow * 32 + c0], s1v = sinT[srow * 32 + c0 + 1];
        float km = ((float)srow < mlen_n) ? 1.f : 0.f;
        float ka0 = bf2f(ka.x), ka1 = bf2f(ka.y), kb0 = bf2f(kb.x), kb1 = bf2f(kb.y);
        kr0 = elu1(ka0 * c0v - kb0 * s0v) * km;
        kr1 = elu1(ka1 * c1v - kb1 * s1v) * km;
        kr2 = elu1(kb0 * c0v + ka0 * s0v) * km;
        kr3 = elu1(kb1 * c1v + ka1 * s1v) * km;
        v0 = bf2f(va.x); v1 = bf2f(va.y); v2 = bf2f(vb.x); v3 = bf2f(vb.y);
      }
      const int sh = sl_ >> 3, slow = sl_ & 7;
      sKT[(c0)      * 64 + (((sh ^ ((c0)      & 7)) << 3) | slow)] = f2bf(kr0);
      sKT[(c0 + 1)  * 64 + (((sh ^ ((c0 + 1)  & 7)) << 3) | slow)] = f2bf(kr1);
      sKT[(c0 + 32) * 64 + (((sh ^ ((c0 + 32) & 7)) << 3) | slow)] = f2bf(kr2);
      sKT[(c0 + 33) * 64 + (((sh ^ ((c0 + 33) & 7)) << 3) | slow)] = f2bf(kr3);
      sVT[(c0)      * 64 + (((sh ^ ((c0)      & 7)) << 3) | slow)] = f2bf(v0);
      sVT[(c0 + 1)  * 64 + (((sh ^ ((c0 + 1)  & 7)) << 3) | slow)] = f2bf(v1);
      sVT[(c0 + 32) * 64 + (((sh ^ ((c0 + 32) & 7)) << 3) | slow)] = f2bf(v2);
      sVT[(c0 + 33) * 64 + (((sh ^ ((c0 + 33) & 7)) << 3) | slow)] = f2bf(v3);
    }
    __syncthreads();
    __builtin_amdgcn_s_setprio(1);
#pragma unroll
    for (int kk = 0; kk < 2; ++kk) {
      const int sl = ((lg + kk * 4) ^ lr7) * 8;
      bf16x8 bk = *(const bf16x8*)(sKT + (w * 16 + lr) * 64 + sl);
#pragma unroll
      for (int mt = 0; mt < 5; ++mt) {
        bf16x8 av = *(const bf16x8*)(sVT + (mt * 16 + lr) * 64 + sl);
        accA[mt] = __builtin_amdgcn_mfma_f32_16x16x32_bf16(av, bk, accA[mt], 0, 0, 0);
      }
    }
    __builtin_amdgcn_s_setprio(0);
    __syncthreads();
  }
  {
    const int d = w * 16 + lr;
    const int dh = d >> 3, dlow = d & 7;
#pragma unroll
    for (int mt = 0; mt < 5; ++mt) {
#pragma unroll
      for (int j = 0; j < 4; ++j) {
        const int m = mt * 16 + lg * 4 + j;
        sKVT[m * 64 + (((dh ^ (m & 7)) << 3) | dlow)] = f2bf(accA[mt][j]);
      }
    }
  }
  __syncthreads();

  for (int qt = 0; qt < 5; ++qt) {
#pragma unroll
    for (int pass = 0; pass < 4; ++pass) {
      const int slot = pass * 256 + t;
      const int ll = slot >> 4;
      const int j = slot & 15;
      const int c0 = 2 * j;
      int lq = qt * 64 + ll;
      const int lqc = (lq < SEQ) ? lq : (SEQ - 1);
      const unsigned short* Rw = QKV + ((long)(n * SEQ + lqc)) * QKVD + h * 64;
      ushort2 qa = *(const ushort2*)(Rw + c0);
      ushort2 qb = *(const ushort2*)(Rw + c0 + 32);
      float c0v = cosT[lqc * 32 + c0], c1v = cosT[lqc * 32 + c0 + 1];
      float s0v = sinT[lqc * 32 + c0], s1v = sinT[lqc * 32 + c0 + 1];
      float a0 = bf2f(qa.x), a1 = bf2f(qa.y), b0 = bf2f(qb.x), b1 = bf2f(qb.y);
      float q0 = elu1(a0 * c0v - b0 * s0v);
      float q1 = elu1(a1 * c1v - b1 * s1v);
      float q2 = elu1(b0 * c0v + a0 * s0v);
      float q3 = elu1(b1 * c1v + a1 * s1v);
      const int l7 = ll & 7;
      ushort2 p0; p0.x = f2bf(q0); p0.y = f2bf(q1);
      ushort2 p1; p1.x = f2bf(q2); p1.y = f2bf(q3);
      *(ushort2*)(sQ + ll * 64 + ((((c0 >> 3) ^ l7) << 3) | (c0 & 7))) = p0;
      *(ushort2*)(sQ + ll * 64 + (((((c0 + 32) >> 3) ^ l7) << 3) | (c0 & 7))) = p1;
    }
    __syncthreads();
    f32x4 accB[5];
#pragma unroll
    for (int nt = 0; nt < 5; ++nt) accB[nt] = (f32x4){0.f, 0.f, 0.f, 0.f};
    __builtin_amdgcn_s_setprio(1);
#pragma unroll
    for (int kk = 0; kk < 2; ++kk) {
      const int sl = ((lg + kk * 4) ^ lr7) * 8;
      bf16x8 aq = *(const bf16x8*)(sQ + (w * 16 + lr) * 64 + sl);
#pragma unroll
      for (int nt = 0; nt < 5; ++nt) {
        bf16x8 bkv = *(const bf16x8*)(sKVT + (nt * 16 + lr) * 64 + sl);
        accB[nt] = __builtin_amdgcn_mfma_f32_16x16x32_bf16(aq, bkv, accB[nt], 0, 0, 0);
      }
    }
    __builtin_amdgcn_s_setprio(0);
#pragma unroll
    for (int j = 0; j < 4; ++j) {
      float z = __shfl(accB[4][j], ln & 48, 64);
      float zr = 1.f / (z + 1e-6f);
      const int lq = qt * 64 + w * 16 + lg * 4 + j;
      if (lq < SEQ) {
        const long orow = ((long)(n * SEQ + lq)) * DIMD + h * 64;
#pragma unroll
        for (int nt = 0; nt < 4; ++nt)
          Obf[orow + nt * 16 + lr] = f2bf(accB[nt][j] * zr);
      }
    }
    __syncthreads();
  }
}

// y = LN(x + a) -> fp32 + bf16. A is bf16 (GEMM epilogues emit bf16).
__global__ __launch_bounds__(128)
void add_ln_k(const float* __restrict__ X, const unsigned short* __restrict__ A,
              const float* __restrict__ g, const float* __restrict__ b,
              float* __restrict__ Yf, unsigned short* __restrict__ Ybf) {
  int row = blockIdx.x, t = threadIdx.x;
  long base = (long)row * DIMD + t * 4;
  float4 xv = *(const float4*)(X + base);
  ushort4 au = *(const ushort4*)(A + base);
  float4 s;
  s.x = xv.x + bf2f(au.x); s.y = xv.y + bf2f(au.y);
  s.z = xv.z + bf2f(au.z); s.w = xv.w + bf2f(au.w);
  float sum = s.x + s.y + s.z + s.w;
  float sq = s.x * s.x + s.y * s.y + s.z * s.z + s.w * s.w;
#pragma unroll
  for (int of = 1; of < 64; of <<= 1) { sum += __shfl_xor(sum, of, 64); sq += __shfl_xor(sq, of, 64); }
  __shared__ float red[4];
  if ((t & 63) == 0) { red[(t >> 6) * 2] = sum; red[(t >> 6) * 2 + 1] = sq; }
  __syncthreads();
  sum = red[0] + red[2]; sq = red[1] + red[3];
  float mean = sum * (1.f / 512.f);
  float var = sq * (1.f / 512.f) - mean * mean;
  float rstd = rsqrtf(var + 1e-5f);
  float4 gv = *(const float4*)(g + t * 4);
  float4 bv = *(const float4*)(b + t * 4);
  float4 y;
  y.x = (s.x - mean) * rstd * gv.x + bv.x;
  y.y = (s.y - mean) * rstd * gv.y + bv.y;
  y.z = (s.z - mean) * rstd * gv.z + bv.z;
  y.w = (s.w - mean) * rstd * gv.w + bv.w;
  *(float4*)(Yf + base) = y;
  ushort4 o; o.x = f2bf(y.x); o.y = f2bf(y.y); o.z = f2bf(y.z); o.w = f2bf(y.w);
  *(ushort4*)(Ybf + base) = o;
}

// final LN + output heads. grid MROWS, block 128. out fp32: [32 global][8192 local]
__global__ __launch_bounds__(128)
void final_head_k(const float* __restrict__ X, const float* __restrict__ g, const float* __restrict__ b,
                  const float* __restrict__ condemb, const int* __restrict__ cond,
                  const float* __restrict__ outgW, const float* __restrict__ outgb,
                  const float* __restrict__ outlW, const float* __restrict__ outlb,
                  float* __restrict__ out) {
  int row = blockIdx.x, t = threadIdx.x;
  int n = row / SEQ, s = row % SEQ;
  long base = (long)row * DIMD + t * 4;
  float4 xv = *(const float4*)(X + base);
  float sum = xv.x + xv.y + xv.z + xv.w;
  float sq = xv.x * xv.x + xv.y * xv.y + xv.z * xv.z + xv.w * xv.w;
#pragma unroll
  for (int of = 1; of < 64; of <<= 1) { sum += __shfl_xor(sum, of, 64); sq += __shfl_xor(sq, of, 64); }
  __shared__ float red[4];
  if ((t & 63) == 0) { red[(t >> 6) * 2] = sum; red[(t >> 6) * 2 + 1] = sq; }
  __syncthreads();
  sum = red[0] + red[2]; sq = red[1] + red[3];
  float mean = sum * (1.f / 512.f);
  float var = sq * (1.f / 512.f) - mean * mean;
  float rstd = rsqrtf(var + 1e-5f);
  float4 gv = *(const float4*)(g + t * 4);
  float4 bv = *(const float4*)(b + t * 4);
  const float* wsel = (s == 0) ? outgW : outlW;
  const float* ce = condemb + (long)cond[n] * DIMD;
  float4 wv = *(const float4*)(wsel + t * 4);
  float4 cv = *(const float4*)(ce + t * 4);
  float l0 = (xv.x - mean) * rstd * gv.x + bv.x;
  float l1 = (xv.y - mean) * rstd * gv.y + bv.y;
  float l2 = (xv.z - mean) * rstd * gv.z + bv.z;
  float l3 = (xv.w - mean) * rstd * gv.w + bv.w;
  float pl = l0 * wv.x + l1 * wv.y + l2 * wv.z + l3 * wv.w;
  float pc = l0 * cv.x + l1 * cv.y + l2 * cv.z + l3 * cv.w;
#pragma unroll
  for (int of = 1; of < 64; of <<= 1) { pl += __shfl_xor(pl, of, 64); pc += __shfl_xor(pc, of, 64); }
  __shared__ float red2[4];
  if ((t & 63) == 0) { red2[(t >> 6) * 2] = pl; red2[(t >> 6) * 2 + 1] = pc; }
  __syncthreads();
  if (t == 0) {
    float res = red2[0] + red2[2] + red2[1] + red2[3] + ((s == 0) ? outgb[0] : outlb[0]);
    long oi = (s == 0) ? (long)n : (32 + (long)n * 256 + (s - 1));
    out[oi] = res;
  }
}

// ---------------------------------------------------------------- host
extern "C" void kernel_launch(void* const* d_in, const int* in_sizes, int n_in,
                              void* d_out, int out_size, void* d_ws, size_t ws_size,
                              hipStream_t stream) {
  const float* inputs    = (const float*)d_in[0];
  const float* input_mask= (const float*)d_in[1];
  const int*   cond      = (const int*)d_in[2];
  const float* emb_W     = (const float*)d_in[3];
  const float* emb_b     = (const float*)d_in[4];
  const float* conv_W    = (const float*)d_in[5];
  const float* conv_b    = (const float*)d_in[6];
  const float* pos_emb   = (const float*)d_in[7];
  const float* cls_token = (const float*)d_in[8];
  const float* Wq = (const float*)d_in[9];   const float* bq = (const float*)d_in[10];
  const float* Wk = (const float*)d_in[11];  const float* bk = (const float*)d_in[12];
  const float* Wv = (const float*)d_in[13];  const float* bv = (const float*)d_in[14];
  const float* Wo = (const float*)d_in[15];  const float* bo = (const float*)d_in[16];
  const float* ln1_g = (const float*)d_in[17]; const float* ln1_b = (const float*)d_in[18];
  const float* W1 = (const float*)d_in[19];  const float* b1 = (const float*)d_in[20];
  const float* W2 = (const float*)d_in[21];  const float* b2 = (const float*)d_in[22];
  const float* ln2_g = (const float*)d_in[23]; const float* ln2_b = (const float*)d_in[24];
  const float* normf_g = (const float*)d_in[25]; const float* normf_b = (const float*)d_in[26];
  const float* cond_emb = (const float*)d_in[27];
  const float* outg_W = (const float*)d_in[28]; const float* outg_b = (const float*)d_in[29];
  const float* outl_W = (const float*)d_in[30]; const float* outl_b = (const float*)d_in[31];

  char* ws = (char*)d_ws;
  size_t off = 0;
  auto alloc = [&](size_t bytes) -> char* {
    char* p = ws + off;
    off += (bytes + 255) & ~(size_t)255;
    return p;
  };
  unsigned short* WeT   = (unsigned short*)alloc((size_t)512 * 4096 * 2);
  float*          embWT = (float*)alloc((size_t)512 * 256 * 4);
  float*          bias2 = (float*)alloc(512 * 4);
  float*          cosT  = (float*)alloc(SEQ * 32 * 4);
  float*          sinT  = (float*)alloc(SEQ * 32 * 4);
  float*          mlen  = (float*)alloc(32 * 4);
  unsigned short* Wqkv  = (unsigned short*)alloc((size_t)NLYR * QKVD * 512 * 2);
  float*          bqkv  = (float*)alloc((size_t)NLYR * QKVD * 4);
  unsigned short* WoT = (unsigned short*)alloc((size_t)NLYR * 512 * 512 * 2);
  unsigned short* W1T = (unsigned short*)alloc((size_t)NLYR * 2048 * 512 * 2);
  unsigned short* W2T = (unsigned short*)alloc((size_t)NLYR * 512 * 2048 * 2);
  // in_bf (64 MB) only needed before the stem GEMM; tqkv_bf (25 MB) aliases it.
  char*           big  = alloc((size_t)MSTEM * KSTEM * 2);
  unsigned short* in_bf   = (unsigned short*)big;
  unsigned short* tqkv_bf = (unsigned short*)big;
  float*          x_f  = (float*)alloc((size_t)MPAD * DIMD * 4);
  unsigned short* x_bf = (unsigned short*)alloc((size_t)MPAD * DIMD * 2);
  float*          y_f  = (float*)alloc((size_t)MPAD * DIMD * 4);
  unsigned short* y_bf = (unsigned short*)alloc((size_t)MPAD * DIMD * 2);
  float*          t0   = (float*)alloc((size_t)MPAD * DIMD * 4);
  unsigned short* t0bf = (unsigned short*)alloc((size_t)MPAD * DIMD * 2);
  unsigned short* attn_bf = (unsigned short*)alloc((size_t)MPAD * DIMD * 2);
  unsigned short* h_bf = (unsigned short*)alloc((size_t)MPAD * FFD * 2);
  (void)ws_size; (void)in_sizes; (void)n_in; (void)out_size;

  dim3 tb(32, 8);
  // fused QKV weight: per layer rows [0..512)=Wq^T, [512..1024)=Wk^T, [1024..1536)=Wv^T
  transpose_k<1><<<dim3(16, 16, 8), tb, 0, stream>>>(Wq, Wqkv, 512, 512, (long)QKVD * 512);
  transpose_k<1><<<dim3(16, 16, 8), tb, 0, stream>>>(Wk, Wqkv + (size_t)512 * 512, 512, 512, (long)QKVD * 512);
  transpose_k<1><<<dim3(16, 16, 8), tb, 0, stream>>>(Wv, Wqkv + (size_t)1024 * 512, 512, 512, (long)QKVD * 512);
  transpose_k<1><<<dim3(16, 16, 8), tb, 0, stream>>>(Wo, WoT, 512, 512, (long)512 * 512);
  transpose_k<1><<<dim3(16, 64, 8), tb, 0, stream>>>(W1, W1T, 512, 2048, (long)512 * 2048);
  transpose_k<1><<<dim3(64, 16, 8), tb, 0, stream>>>(W2, W2T, 2048, 512, (long)2048 * 512);
  transpose_k<0><<<dim3(8, 16, 1), tb, 0, stream>>>(emb_W, embWT, 256, 512, 0);
  concat_bias_k<<<(NLYR * QKVD + 255) / 256, 256, 0, stream>>>(bq, bk, bv, bqkv);
  weff_kernel<<<512, 256, 0, stream>>>(embWT, conv_W, emb_b, conv_b, WeT, bias2);
  f32_to_bf16_k<<<4096, 256, 0, stream>>>(inputs, in_bf, (long)MSTEM * KSTEM / 4);
  rotary_k<<<(SEQ * 32 + 255) / 256, 256, 0, stream>>>(cosT, sinT);
  masklen_k<<<32, 256, 0, stream>>>(input_mask, mlen);

  // stem GEMM: (8192 x 4096) @ (4096 x 512) -> t0 fp32  [grid 64x8 = 512]
  gemm_bt<0><<<512, 256, 0, stream>>>(in_bf, WeT, nullptr, t0, KSTEM, DIMD, 8);
  assemble_x<<<(MROWS * 128 + 255) / 256, 256, 0, stream>>>(t0, bias2, pos_emb, cls_token, x_f, x_bf);

  for (int i = 0; i < NLYR; ++i) {
    const unsigned short* wqkv = Wqkv + (size_t)i * QKVD * 512;
    const unsigned short* wo = WoT + (size_t)i * 512 * 512;
    const unsigned short* w1 = W1T + (size_t)i * 2048 * 512;
    const unsigned short* w2 = W2T + (size_t)i * 512 * 2048;
    // fused QKV -> bf16  [grid 65x24 = 1560]
    gemm_bt<2><<<65 * 24, 256, 0, stream>>>(x_bf, wqkv, bqkv + i * QKVD, tqkv_bf, 512, QKVD, 24);
    attn_fused_k<<<256, 256, 0, stream>>>(tqkv_bf, cosT, sinT, mlen, attn_bf);
    // O-proj -> bf16  [grid 65x8 = 520]
    gemm_bt<2><<<65 * 8, 256, 0, stream>>>(attn_bf, wo, bo + i * 512, t0bf, 512, 512, 8);
    add_ln_k<<<MROWS, 128, 0, stream>>>(x_f, t0bf, ln1_g + i * 512, ln1_b + i * 512, y_f, y_bf);
    // FF1 (gelu) -> bf16  [grid 65x32 = 2080]
    gemm_bt<1><<<65 * 32, 256, 0, stream>>>(y_bf, w1, b1 + i * 2048, h_bf, 512, 2048, 32);
    // FF2 -> bf16  [grid 65x8 = 520]
    gemm_bt<2><<<65 * 8, 256, 0, stream>>>(h_bf, w2, b2 + i * 512, t0bf, 2048, 512, 8);
    add_ln_k<<<MROWS, 128, 0, stream>>>(y_f, t0bf, ln2_g + i * 512, ln2_b + i * 512, x_f, x_bf);
  }
  final_head_k<<<MROWS, 128, 0, stream>>>(x_f, normf_g, normf_b, cond_emb, cond,
                                          outg_W, outg_b, outl_W, outl_b, (float*)d_out);
}

// Round 15
// 1427.640 us; speedup vs baseline: 1.1465x; 1.0456x over previous
//
#include <hip/hip_runtime.h>

typedef __attribute__((ext_vector_type(4))) float f32x4;
typedef __attribute__((ext_vector_type(8))) __bf16 bf16x8;

#define SEQ   257
#define NBATCH 32
#define DIMD  512
#define FFD   2048
#define NLYR  8
#define MROWS (NBATCH*SEQ)   /* 8224 */
#define MPAD  8320           /* 65*128 */
#define MSTEM 8192
#define KSTEM 4096
#define QKVD  1536

__device__ __forceinline__ unsigned short f2bf(float f) {
  unsigned int u = __float_as_uint(f);
  return (unsigned short)((u + 0x7FFFu + ((u >> 16) & 1u)) >> 16);
}
__device__ __forceinline__ float bf2f(unsigned short u) {
  return __uint_as_float(((unsigned int)u) << 16);
}
__device__ __forceinline__ float elu1(float x) { return x > 0.f ? x + 1.f : expf(x); }

__device__ __forceinline__ void gload16(const void* g, void* l) {
  __builtin_amdgcn_global_load_lds((__attribute__((address_space(1))) void*)g,
                                   (__attribute__((address_space(3))) void*)l, 16, 0, 0);
}

// ---------------------------------------------------------------- GEMM (2-phase, BK=64)
// C[M,N] = A[M,K](bf16) * BT[N,K](bf16) + bias.  BM=128, BN=64, waves 4x1, MW=2/NW=4;
// 48 KB dbuf LDS -> 3 blocks/CU.  Local optimum across 4 schedule probes (r10/r12/r13).
// EPI 1: gelu -> bf16. EPI 2: plain bf16. EPI 3: + residual Xres (bf16) -> bf16.
// 1-D grid, by-fastest linearization + BIJECTIVE XCD-chunked swizzle.
// LDS XOR-swizzled (16B slot s of row r holds global slot s^(r&7)).
template<int EPI>
__global__ __launch_bounds__(256)
void gemm_bt(const unsigned short* __restrict__ A,
             const unsigned short* __restrict__ BT,
             const float* __restrict__ bias,
             const unsigned short* __restrict__ Xres,
             void* __restrict__ Cout, int K, int Nn, int NBY) {
  constexpr int MW = 2;
  constexpr int NW = 4;
  constexpr int BM = 128;
  constexpr int BN = 64;
  __shared__ __align__(16) unsigned short sA[2][BM * 64];
  __shared__ __align__(16) unsigned short sB[2][BN * 64];
  const int tid = threadIdx.x;
  const int w = tid >> 6, l = tid & 63;
  const int nwg = gridDim.x;
  const int q = nwg >> 3, r = nwg & 7;
  const int xcd = blockIdx.x & 7, idx = blockIdx.x >> 3;
  const int wg = (xcd < r) ? (xcd * (q + 1) + idx) : (r * (q + 1) + (xcd - r) * q + idx);
  const int bx = wg / NBY, by = wg % NBY;
  const long tm = (long)bx * BM;
  const long tn = (long)by * BN;
  const int lr = l & 15, lg = l >> 4;
  const int lr7 = lr & 7;

  auto stage = [&](int buf, int t) {
    const long k0 = (long)t * 64;
#pragma unroll
    for (int j = 0; j < 4; ++j) {
      const int ch = j * 256 + tid;
      const int rr = ch >> 3, s = ch & 7;
      gload16(A + (tm + rr) * (long)K + k0 + ((s ^ (rr & 7)) * 8), sA[buf] + ch * 8);
    }
#pragma unroll
    for (int j = 0; j < 2; ++j) {
      const int ch = j * 256 + tid;
      const int rr = ch >> 3, s = ch & 7;
      gload16(BT + (tn + rr) * (long)K + k0 + ((s ^ (rr & 7)) * 8), sB[buf] + ch * 8);
    }
  };

  f32x4 acc[MW][NW];
#pragma unroll
  for (int m = 0; m < MW; ++m)
#pragma unroll
    for (int n = 0; n < NW; ++n) acc[m][n] = (f32x4){0.f, 0.f, 0.f, 0.f};

  const int nt = K >> 6;
  stage(0, 0);
  for (int t = 0; t < nt; ++t) {
    const int cur = t & 1;
    __syncthreads();
    if (t + 1 < nt) stage(cur ^ 1, t + 1);
#pragma unroll
    for (int kk = 0; kk < 2; ++kk) {
      const int sl = ((lg + kk * 4) ^ lr7) * 8;
      bf16x8 af[MW], bfr[NW];
#pragma unroll
      for (int m = 0; m < MW; ++m)
        af[m] = *(const bf16x8*)(sA[cur] + (w * MW * 16 + m * 16 + lr) * 64 + sl);
#pragma unroll
      for (int n = 0; n < NW; ++n)
        bfr[n] = *(const bf16x8*)(sB[cur] + (n * 16 + lr) * 64 + sl);
#pragma unroll
      for (int m = 0; m < MW; ++m)
#pragma unroll
        for (int n = 0; n < NW; ++n)
          acc[m][n] = __builtin_amdgcn_mfma_f32_16x16x32_bf16(af[m], bfr[n], acc[m][n], 0, 0, 0);
    }
  }
#pragma unroll
  for (int m = 0; m < MW; ++m) {
    const long gr0 = tm + w * MW * 16 + m * 16 + lg * 4;
#pragma unroll
    for (int n = 0; n < NW; ++n) {
      const long gc = tn + n * 16 + lr;
      const float bv = bias ? bias[gc] : 0.f;
#pragma unroll
      for (int j = 0; j < 4; ++j) {
        float v = acc[m][n][j] + bv;
        if (EPI == 1) {
          float g = 0.5f * v * (1.f + erff(v * 0.70710678118f));
          ((unsigned short*)Cout)[(gr0 + j) * (long)Nn + gc] = f2bf(g);
        } else if (EPI == 3) {
          v += bf2f(Xres[(gr0 + j) * (long)Nn + gc]);
          ((unsigned short*)Cout)[(gr0 + j) * (long)Nn + gc] = f2bf(v);
        } else {
          ((unsigned short*)Cout)[(gr0 + j) * (long)Nn + gc] = f2bf(v);
        }
      }
    }
  }
}

// ------------------------------------------------- batched transpose (fp32 -> bf16/fp32)
template<int OUT_BF>
__global__ void transpose_k(const float* __restrict__ src, void* __restrict__ dst,
                            int K, int N, long dstZ) {
  __shared__ float t[32][33];
  const long lz = blockIdx.z;
  const float* S = src + lz * (long)K * N;
  const long k0 = (long)blockIdx.x * 32, n0 = (long)blockIdx.y * 32;
  for (int i = threadIdx.y; i < 32; i += 8)
    t[i][threadIdx.x] = S[(k0 + i) * (long)N + n0 + threadIdx.x];
  __syncthreads();
  for (int i = threadIdx.y; i < 32; i += 8) {
    long o = lz * dstZ + (n0 + i) * (long)K + k0 + threadIdx.x;
    float val = t[threadIdx.x][i];
    if (OUT_BF) ((unsigned short*)dst)[o] = f2bf(val);
    else ((float*)dst)[o] = val;
  }
}

// ------------------------------------------------- W_eff: WeT[o, p*256+c] + fused stem bias
__global__ __launch_bounds__(256)
void weff_kernel(const float* __restrict__ embWT, const float* __restrict__ convW,
                 const float* __restrict__ emb_b, const float* __restrict__ conv_b,
                 unsigned short* __restrict__ WeT, float* __restrict__ bias2) {
  __shared__ float sc[8192];
  const int o = blockIdx.x;
  const float* C = convW + (long)o * 8192;
  for (int i = threadIdx.x; i < 8192; i += 256) sc[i] = C[i];
  __syncthreads();
  const int c = threadIdx.x;
  float acc[16];
#pragma unroll
  for (int p = 0; p < 16; ++p) acc[p] = 0.f;
  for (int d = 0; d < 512; ++d) {
    float ev = embWT[d * 256 + c];
#pragma unroll
    for (int p = 0; p < 16; ++p) acc[p] += ev * sc[d * 16 + p];
  }
#pragma unroll
  for (int p = 0; p < 16; ++p) WeT[(long)o * 4096 + p * 256 + c] = f2bf(acc[p]);
  float lb = 0.f;
  for (int d = c; d < 512; d += 256) {
    float s16 = 0.f;
#pragma unroll
    for (int p = 0; p < 16; ++p) s16 += sc[d * 16 + p];
    lb += emb_b[d] * s16;
  }
#pragma unroll
  for (int of = 1; of < 64; of <<= 1) lb += __shfl_xor(lb, of, 64);
  __shared__ float red[4];
  if ((threadIdx.x & 63) == 0) red[threadIdx.x >> 6] = lb;
  __syncthreads();
  if (threadIdx.x == 0) bias2[o] = red[0] + red[1] + red[2] + red[3] + conv_b[o];
}

// ------------------------------------------------- misc small kernels
__global__ void f32_to_bf16_k(const float* __restrict__ in, unsigned short* __restrict__ out, long n4) {
  long i = (long)blockIdx.x * blockDim.x + threadIdx.x;
  const long stride = (long)gridDim.x * blockDim.x;
  for (; i < n4; i += stride) {
    float4 v = ((const float4*)in)[i];
    ushort4 o; o.x = f2bf(v.x); o.y = f2bf(v.y); o.z = f2bf(v.z); o.w = f2bf(v.w);
    ((ushort4*)out)[i] = o;
  }
}

__global__ void rotary_k(float* __restrict__ cosT, float* __restrict__ sinT) {
  int idx = blockIdx.x * 256 + threadIdx.x;
  if (idx >= SEQ * 32) return;
  int s = idx >> 5, j = idx & 31;
  float inv = expf(-(float)(2 * j) * (1.f / 64.f) * 9.210340371976184f);
  float a = (float)s * inv;
  cosT[idx] = cosf(a);
  sinT[idx] = sinf(a);
}

__global__ void concat_bias_k(const float* __restrict__ bq, const float* __restrict__ bk,
                              const float* __restrict__ bv, float* __restrict__ bqkv) {
  int idx = blockIdx.x * 256 + threadIdx.x;
  if (idx >= NLYR * QKVD) return;
  int i = idx / QKVD, j = idx % QKVD;
  float v;
  if (j < 512) v = bq[i * 512 + j];
  else if (j < 1024) v = bk[i * 512 + j - 512];
  else v = bv[i * 512 + j - 1024];
  bqkv[idx] = v;
}

__global__ __launch_bounds__(256)
void masklen_k(const float* __restrict__ mask, float* __restrict__ mlen) {
  int n = blockIdx.x;
  float s = 0.f;
  for (int i = threadIdx.x; i < 4096; i += 256) s += mask[(long)n * 4096 + i];
#pragma unroll
  for (int of = 1; of < 64; of <<= 1) s += __shfl_xor(s, of, 64);
  __shared__ float red[4];
  if ((threadIdx.x & 63) == 0) red[threadIdx.x >> 6] = s;
  __syncthreads();
  if (threadIdx.x == 0) mlen[n] = ceilf((1.f + red[0] + red[1] + red[2] + red[3]) * (1.f / 16.f));
}

// assemble x from bf16 stem output; writes bf16 residual stream only.
__global__ void assemble_x(const unsigned short* __restrict__ stem, const float* __restrict__ bias2,
                           const float* __restrict__ posemb, const float* __restrict__ cls,
                           unsigned short* __restrict__ Xbf) {
  long idx = (long)blockIdx.x * 256 + threadIdx.x;
  if (idx >= (long)MROWS * 128) return;
  long row = idx >> 7;
  int c4 = (int)(idx & 127) * 4;
  int n = (int)(row / SEQ), s = (int)(row % SEQ);
  float4 p = *(const float4*)(posemb + (long)s * DIMD + c4);
  float4 v;
  if (s == 0) {
    float4 cv = *(const float4*)(cls + c4);
    v.x = cv.x + p.x; v.y = cv.y + p.y; v.z = cv.z + p.z; v.w = cv.w + p.w;
  } else {
    ushort4 st = *(const ushort4*)(stem + ((long)(n * 256 + s - 1)) * DIMD + c4);
    float4 b2 = *(const float4*)(bias2 + c4);
    v.x = bf2f(st.x) + b2.x + p.x; v.y = bf2f(st.y) + b2.y + p.y;
    v.z = bf2f(st.z) + b2.z + p.z; v.w = bf2f(st.w) + b2.w + p.w;
  }
  ushort4 o; o.x = f2bf(v.x); o.y = f2bf(v.y); o.z = f2bf(v.z); o.w = f2bf(v.w);
  *(ushort4*)(Xbf + row * DIMD + c4) = o;
}

// ------------------------------------------------- fused MFMA linear attention
// One block per (n,h), 256 threads (4 waves). Round-14 version (setprio kept, noise-level).
__global__ __launch_bounds__(256)
void attn_fused_k(const unsigned short* __restrict__ QKV,
                  const float* __restrict__ cosT, const float* __restrict__ sinT,
                  const float* __restrict__ mlen, unsigned short* __restrict__ Obf) {
  const int n = blockIdx.x >> 3, h = blockIdx.x & 7;
  __shared__ __align__(16) unsigned short sKT[64 * 64];
  __shared__ __align__(16) unsigned short sVT[80 * 64];
  __shared__ __align__(16) unsigned short sKVT[80 * 64];
  __shared__ __align__(16) unsigned short sQ[64 * 64];
  const int t = threadIdx.x;
  const int w = t >> 6, ln = t & 63;
  const int lr = ln & 15, lg = ln >> 4;
  const int lr7 = lr & 7;
  const float mlen_n = mlen[n];

  {
    unsigned short val = (t < 16) ? (unsigned short)0x3F80 : (unsigned short)0;
    ushort4 iv; iv.x = val; iv.y = val; iv.z = val; iv.w = val;
    *(ushort4*)(sVT + 64 * 64 + t * 4) = iv;
  }

  f32x4 accA[5];
#pragma unroll
  for (int mt = 0; mt < 5; ++mt) accA[mt] = (f32x4){0.f, 0.f, 0.f, 0.f};

  for (int ch = 0; ch < 5; ++ch) {
#pragma unroll
    for (int pass = 0; pass < 4; ++pass) {
      const int slot = pass * 256 + t;
      const int sl_ = slot >> 4;
      const int j = slot & 15;
      const int c0 = 2 * j;
      const int srow = ch * 64 + sl_;
      float kr0 = 0.f, kr1 = 0.f, kr2 = 0.f, kr3 = 0.f;
      float v0 = 0.f, v1 = 0.f, v2 = 0.f, v3 = 0.f;
      if (srow < SEQ) {
        const unsigned short* Rw = QKV + ((long)(n * SEQ + srow)) * QKVD + h * 64;
        ushort2 ka = *(const ushort2*)(Rw + 512 + c0);
        ushort2 kb = *(const ushort2*)(Rw + 512 + c0 + 32);
        ushort2 va = *(const ushort2*)(Rw + 1024 + c0);
        ushort2 vb = *(const ushort2*)(Rw + 1024 + c0 + 32);
        float c0v = cosT[srow * 32 + c0], c1v = cosT[srow * 32 + c0 + 1];
        float s0v = sinT[srow * 32 + c0], s1v = sinT[srow * 32 + c0 + 1];
        float km = ((float)srow < mlen_n) ? 1.f : 0.f;
        float ka0 = bf2f(ka.x), ka1 = bf2f(ka.y), kb0 = bf2f(kb.x), kb1 = bf2f(kb.y);
        kr0 = elu1(ka0 * c0v - kb0 * s0v) * km;
        kr1 = elu1(ka1 * c1v - kb1 * s1v) * km;
        kr2 = elu1(kb0 * c0v + ka0 * s0v) * km;
        kr3 = elu1(kb1 * c1v + ka1 * s1v) * km;
        v0 = bf2f(va.x); v1 = bf2f(va.y); v2 = bf2f(vb.x); v3 = bf2f(vb.y);
      }
      const int sh = sl_ >> 3, slow = sl_ & 7;
      sKT[(c0)      * 64 + (((sh ^ ((c0)      & 7)) << 3) | slow)] = f2bf(kr0);
      sKT[(c0 + 1)  * 64 + (((sh ^ ((c0 + 1)  & 7)) << 3) | slow)] = f2bf(kr1);
      sKT[(c0 + 32) * 64 + (((sh ^ ((c0 + 32) & 7)) << 3) | slow)] = f2bf(kr2);
      sKT[(c0 + 33) * 64 + (((sh ^ ((c0 + 33) & 7)) << 3) | slow)] = f2bf(kr3);
      sVT[(c0)      * 64 + (((sh ^ ((c0)      & 7)) << 3) | slow)] = f2bf(v0);
      sVT[(c0 + 1)  * 64 + (((sh ^ ((c0 + 1)  & 7)) << 3) | slow)] = f2bf(v1);
      sVT[(c0 + 32) * 64 + (((sh ^ ((c0 + 32) & 7)) << 3) | slow)] = f2bf(v2);
      sVT[(c0 + 33) * 64 + (((sh ^ ((c0 + 33) & 7)) << 3) | slow)] = f2bf(v3);
    }
    __syncthreads();
    __builtin_amdgcn_s_setprio(1);
#pragma unroll
    for (int kk = 0; kk < 2; ++kk) {
      const int sl = ((lg + kk * 4) ^ lr7) * 8;
      bf16x8 bk = *(const bf16x8*)(sKT + (w * 16 + lr) * 64 + sl);
#pragma unroll
      for (int mt = 0; mt < 5; ++mt) {
        bf16x8 av = *(const bf16x8*)(sVT + (mt * 16 + lr) * 64 + sl);
        accA[mt] = __builtin_amdgcn_mfma_f32_16x16x32_bf16(av, bk, accA[mt], 0, 0, 0);
      }
    }
    __builtin_amdgcn_s_setprio(0);
    __syncthreads();
  }
  {
    const int d = w * 16 + lr;
    const int dh = d >> 3, dlow = d & 7;
#pragma unroll
    for (int mt = 0; mt < 5; ++mt) {
#pragma unroll
      for (int j = 0; j < 4; ++j) {
        const int m = mt * 16 + lg * 4 + j;
        sKVT[m * 64 + (((dh ^ (m & 7)) << 3) | dlow)] = f2bf(accA[mt][j]);
      }
    }
  }
  __syncthreads();

  for (int qt = 0; qt < 5; ++qt) {
#pragma unroll
    for (int pass = 0; pass < 4; ++pass) {
      const int slot = pass * 256 + t;
      const int ll = slot >> 4;
      const int j = slot & 15;
      const int c0 = 2 * j;
      int lq = qt * 64 + ll;
      const int lqc = (lq < SEQ) ? lq : (SEQ - 1);
      const unsigned short* Rw = QKV + ((long)(n * SEQ + lqc)) * QKVD + h * 64;
      ushort2 qa = *(const ushort2*)(Rw + c0);
      ushort2 qb = *(const ushort2*)(Rw + c0 + 32);
      float c0v = cosT[lqc * 32 + c0], c1v = cosT[lqc * 32 + c0 + 1];
      float s0v = sinT[lqc * 32 + c0], s1v = sinT[lqc * 32 + c0 + 1];
      float a0 = bf2f(qa.x), a1 = bf2f(qa.y), b0 = bf2f(qb.x), b1 = bf2f(qb.y);
      float q0 = elu1(a0 * c0v - b0 * s0v);
      float q1 = elu1(a1 * c1v - b1 * s1v);
      float q2 = elu1(b0 * c0v + a0 * s0v);
      float q3 = elu1(b1 * c1v + a1 * s1v);
      const int l7 = ll & 7;
      ushort2 p0; p0.x = f2bf(q0); p0.y = f2bf(q1);
      ushort2 p1; p1.x = f2bf(q2); p1.y = f2bf(q3);
      *(ushort2*)(sQ + ll * 64 + ((((c0 >> 3) ^ l7) << 3) | (c0 & 7))) = p0;
      *(ushort2*)(sQ + ll * 64 + (((((c0 + 32) >> 3) ^ l7) << 3) | (c0 & 7))) = p1;
    }
    __syncthreads();
    f32x4 accB[5];
#pragma unroll
    for (int nt = 0; nt < 5; ++nt) accB[nt] = (f32x4){0.f, 0.f, 0.f, 0.f};
    __builtin_amdgcn_s_setprio(1);
#pragma unroll
    for (int kk = 0; kk < 2; ++kk) {
      const int sl = ((lg + kk * 4) ^ lr7) * 8;
      bf16x8 aq = *(const bf16x8*)(sQ + (w * 16 + lr) * 64 + sl);
#pragma unroll
      for (int nt = 0; nt < 5; ++nt) {
        bf16x8 bkv = *(const bf16x8*)(sKVT + (nt * 16 + lr) * 64 + sl);
        accB[nt] = __builtin_amdgcn_mfma_f32_16x16x32_bf16(aq, bkv, accB[nt], 0, 0, 0);
      }
    }
    __builtin_amdgcn_s_setprio(0);
#pragma unroll
    for (int j = 0; j < 4; ++j) {
      float z = __shfl(accB[4][j], ln & 48, 64);
      float zr = 1.f / (z + 1e-6f);
      const int lq = qt * 64 + w * 16 + lg * 4 + j;
      if (lq < SEQ) {
        const long orow = ((long)(n * SEQ + lq)) * DIMD + h * 64;
#pragma unroll
        for (int nt = 0; nt < 4; ++nt)
          Obf[orow + nt * 16 + lr] = f2bf(accB[nt][j] * zr);
      }
    }
    __syncthreads();
  }
}

// y = LN(s) -> bf16.  s is the bf16 residual stream (residual-add fused into the
// preceding GEMM epilogue). grid MROWS, block 128.
__global__ __launch_bounds__(128)
void ln_k(const unsigned short* __restrict__ S, const float* __restrict__ g,
          const float* __restrict__ b, unsigned short* __restrict__ Ybf) {
  int row = blockIdx.x, t = threadIdx.x;
  long base = (long)row * DIMD + t * 4;
  ushort4 su = *(const ushort4*)(S + base);
  float4 s;
  s.x = bf2f(su.x); s.y = bf2f(su.y); s.z = bf2f(su.z); s.w = bf2f(su.w);
  float sum = s.x + s.y + s.z + s.w;
  float sq = s.x * s.x + s.y * s.y + s.z * s.z + s.w * s.w;
#pragma unroll
  for (int of = 1; of < 64; of <<= 1) { sum += __shfl_xor(sum, of, 64); sq += __shfl_xor(sq, of, 64); }
  __shared__ float red[4];
  if ((t & 63) == 0) { red[(t >> 6) * 2] = sum; red[(t >> 6) * 2 + 1] = sq; }
  __syncthreads();
  sum = red[0] + red[2]; sq = red[1] + red[3];
  float mean = sum * (1.f / 512.f);
  float var = sq * (1.f / 512.f) - mean * mean;
  float rstd = rsqrtf(var + 1e-5f);
  float4 gv = *(const float4*)(g + t * 4);
  float4 bv = *(const float4*)(b + t * 4);
  ushort4 o;
  o.x = f2bf((s.x - mean) * rstd * gv.x + bv.x);
  o.y = f2bf((s.y - mean) * rstd * gv.y + bv.y);
  o.z = f2bf((s.z - mean) * rstd * gv.z + bv.z);
  o.w = f2bf((s.w - mean) * rstd * gv.w + bv.w);
  *(ushort4*)(Ybf + base) = o;
}

// final LN + output heads. X is bf16 residual stream. grid MROWS, block 128.
// out fp32: [32 global][8192 local]
__global__ __launch_bounds__(128)
void final_head_k(const unsigned short* __restrict__ X, const float* __restrict__ g, const float* __restrict__ b,
                  const float* __restrict__ condemb, const int* __restrict__ cond,
                  const float* __restrict__ outgW, const float* __restrict__ outgb,
                  const float* __restrict__ outlW, const float* __restrict__ outlb,
                  float* __restrict__ out) {
  int row = blockIdx.x, t = threadIdx.x;
  int n = row / SEQ, s = row % SEQ;
  long base = (long)row * DIMD + t * 4;
  ushort4 xu = *(const ushort4*)(X + base);
  float4 xv;
  xv.x = bf2f(xu.x); xv.y = bf2f(xu.y); xv.z = bf2f(xu.z); xv.w = bf2f(xu.w);
  float sum = xv.x + xv.y + xv.z + xv.w;
  float sq = xv.x * xv.x + xv.y * xv.y + xv.z * xv.z + xv.w * xv.w;
#pragma unroll
  for (int of = 1; of < 64; of <<= 1) { sum += __shfl_xor(sum, of, 64); sq += __shfl_xor(sq, of, 64); }
  __shared__ float red[4];
  if ((t & 63) == 0) { red[(t >> 6) * 2] = sum; red[(t >> 6) * 2 + 1] = sq; }
  __syncthreads();
  sum = red[0] + red[2]; sq = red[1] + red[3];
  float mean = sum * (1.f / 512.f);
  float var = sq * (1.f / 512.f) - mean * mean;
  float rstd = rsqrtf(var + 1e-5f);
  float4 gv = *(const float4*)(g + t * 4);
  float4 bv = *(const float4*)(b + t * 4);
  const float* wsel = (s == 0) ? outgW : outlW;
  const float* ce = condemb + (long)cond[n] * DIMD;
  float4 wv = *(const float4*)(wsel + t * 4);
  float4 cv = *(const float4*)(ce + t * 4);
  float l0 = (xv.x - mean) * rstd * gv.x + bv.x;
  float l1 = (xv.y - mean) * rstd * gv.y + bv.y;
  float l2 = (xv.z - mean) * rstd * gv.z + bv.z;
  float l3 = (xv.w - mean) * rstd * gv.w + bv.w;
  float pl = l0 * wv.x + l1 * wv.y + l2 * wv.z + l3 * wv.w;
  float pc = l0 * cv.x + l1 * cv.y + l2 * cv.z + l3 * cv.w;
#pragma unroll
  for (int of = 1; of < 64; of <<= 1) { pl += __shfl_xor(pl, of, 64); pc += __shfl_xor(pc, of, 64); }
  __shared__ float red2[4];
  if ((t & 63) == 0) { red2[(t >> 6) * 2] = pl; red2[(t >> 6) * 2 + 1] = pc; }
  __syncthreads();
  if (t == 0) {
    float res = red2[0] + red2[2] + red2[1] + red2[3] + ((s == 0) ? outgb[0] : outlb[0]);
    long oi = (s == 0) ? (long)n : (32 + (long)n * 256 + (s - 1));
    out[oi] = res;
  }
}

// ---------------------------------------------------------------- host
extern "C" void kernel_launch(void* const* d_in, const int* in_sizes, int n_in,
                              void* d_out, int out_size, void* d_ws, size_t ws_size,
                              hipStream_t stream) {
  const float* inputs    = (const float*)d_in[0];
  const float* input_mask= (const float*)d_in[1];
  const int*   cond      = (const int*)d_in[2];
  const float* emb_W     = (const float*)d_in[3];
  const float* emb_b     = (const float*)d_in[4];
  const float* conv_W    = (const float*)d_in[5];
  const float* conv_b    = (const float*)d_in[6];
  const float* pos_emb   = (const float*)d_in[7];
  const float* cls_token = (const float*)d_in[8];
  const float* Wq = (const float*)d_in[9];   const float* bq = (const float*)d_in[10];
  const float* Wk = (const float*)d_in[11];  const float* bk = (const float*)d_in[12];
  const float* Wv = (const float*)d_in[13];  const float* bv = (const float*)d_in[14];
  const float* Wo = (const float*)d_in[15];  const float* bo = (const float*)d_in[16];
  const float* ln1_g = (const float*)d_in[17]; const float* ln1_b = (const float*)d_in[18];
  const float* W1 = (const float*)d_in[19];  const float* b1 = (const float*)d_in[20];
  const float* W2 = (const float*)d_in[21];  const float* b2 = (const float*)d_in[22];
  const float* ln2_g = (const float*)d_in[23]; const float* ln2_b = (const float*)d_in[24];
  const float* normf_g = (const float*)d_in[25]; const float* normf_b = (const float*)d_in[26];
  const float* cond_emb = (const float*)d_in[27];
  const float* outg_W = (const float*)d_in[28]; const float* outg_b = (const float*)d_in[29];
  const float* outl_W = (const float*)d_in[30]; const float* outl_b = (const float*)d_in[31];

  char* ws = (char*)d_ws;
  size_t off = 0;
  auto alloc = [&](size_t bytes) -> char* {
    char* p = ws + off;
    off += (bytes + 255) & ~(size_t)255;
    return p;
  };
  unsigned short* WeT   = (unsigned short*)alloc((size_t)512 * 4096 * 2);
  float*          embWT = (float*)alloc((size_t)512 * 256 * 4);
  float*          bias2 = (float*)alloc(512 * 4);
  float*          cosT  = (float*)alloc(SEQ * 32 * 4);
  float*          sinT  = (float*)alloc(SEQ * 32 * 4);
  float*          mlen  = (float*)alloc(32 * 4);
  unsigned short* Wqkv  = (unsigned short*)alloc((size_t)NLYR * QKVD * 512 * 2);
  float*          bqkv  = (float*)alloc((size_t)NLYR * QKVD * 4);
  unsigned short* WoT = (unsigned short*)alloc((size_t)NLYR * 512 * 512 * 2);
  unsigned short* W1T = (unsigned short*)alloc((size_t)NLYR * 2048 * 512 * 2);
  unsigned short* W2T = (unsigned short*)alloc((size_t)NLYR * 512 * 2048 * 2);
  // in_bf (64 MB) only needed before the stem GEMM; tqkv_bf (25 MB) aliases it.
  char*           big  = alloc((size_t)MSTEM * KSTEM * 2);
  unsigned short* in_bf   = (unsigned short*)big;
  unsigned short* tqkv_bf = (unsigned short*)big;
  unsigned short* t0bf = (unsigned short*)alloc((size_t)MPAD * DIMD * 2);   // stem out / s-scratch
  unsigned short* x_bf = (unsigned short*)alloc((size_t)MPAD * DIMD * 2);
  unsigned short* y_bf = (unsigned short*)alloc((size_t)MPAD * DIMD * 2);
  unsigned short* attn_bf = (unsigned short*)alloc((size_t)MPAD * DIMD * 2);
  unsigned short* h_bf = (unsigned short*)alloc((size_t)MPAD * FFD * 2);
  (void)ws_size; (void)in_sizes; (void)n_in; (void)out_size;

  dim3 tb(32, 8);
  // fused QKV weight: per layer rows [0..512)=Wq^T, [512..1024)=Wk^T, [1024..1536)=Wv^T
  transpose_k<1><<<dim3(16, 16, 8), tb, 0, stream>>>(Wq, Wqkv, 512, 512, (long)QKVD * 512);
  transpose_k<1><<<dim3(16, 16, 8), tb, 0, stream>>>(Wk, Wqkv + (size_t)512 * 512, 512, 512, (long)QKVD * 512);
  transpose_k<1><<<dim3(16, 16, 8), tb, 0, stream>>>(Wv, Wqkv + (size_t)1024 * 512, 512, 512, (long)QKVD * 512);
  transpose_k<1><<<dim3(16, 16, 8), tb, 0, stream>>>(Wo, WoT, 512, 512, (long)512 * 512);
  transpose_k<1><<<dim3(16, 64, 8), tb, 0, stream>>>(W1, W1T, 512, 2048, (long)512 * 2048);
  transpose_k<1><<<dim3(64, 16, 8), tb, 0, stream>>>(W2, W2T, 2048, 512, (long)2048 * 512);
  transpose_k<0><<<dim3(8, 16, 1), tb, 0, stream>>>(emb_W, embWT, 256, 512, 0);
  concat_bias_k<<<(NLYR * QKVD + 255) / 256, 256, 0, stream>>>(bq, bk, bv, bqkv);
  weff_kernel<<<512, 256, 0, stream>>>(embWT, conv_W, emb_b, conv_b, WeT, bias2);
  f32_to_bf16_k<<<4096, 256, 0, stream>>>(inputs, in_bf, (long)MSTEM * KSTEM / 4);
  rotary_k<<<(SEQ * 32 + 255) / 256, 256, 0, stream>>>(cosT, sinT);
  masklen_k<<<32, 256, 0, stream>>>(input_mask, mlen);

  // stem GEMM: (8192 x 4096) @ (4096 x 512) -> bf16  [grid 64x8 = 512]
  gemm_bt<2><<<512, 256, 0, stream>>>(in_bf, WeT, nullptr, nullptr, t0bf, KSTEM, DIMD, 8);
  assemble_x<<<(MROWS * 128 + 255) / 256, 256, 0, stream>>>(t0bf, bias2, pos_emb, cls_token, x_bf);

  for (int i = 0; i < NLYR; ++i) {
    const unsigned short* wqkv = Wqkv + (size_t)i * QKVD * 512;
    const unsigned short* wo = WoT + (size_t)i * 512 * 512;
    const unsigned short* w1 = W1T + (size_t)i * 2048 * 512;
    const unsigned short* w2 = W2T + (size_t)i * 512 * 2048;
    // fused QKV -> bf16  [grid 65x24 = 1560]
    gemm_bt<2><<<65 * 24, 256, 0, stream>>>(x_bf, wqkv, bqkv + i * QKVD, nullptr, tqkv_bf, 512, QKVD, 24);
    attn_fused_k<<<256, 256, 0, stream>>>(tqkv_bf, cosT, sinT, mlen, attn_bf);
    // O-proj + residual(x) -> s bf16  [grid 65x8 = 520]
    gemm_bt<3><<<65 * 8, 256, 0, stream>>>(attn_bf, wo, bo + i * 512, x_bf, t0bf, 512, 512, 8);
    ln_k<<<MROWS, 128, 0, stream>>>(t0bf, ln1_g + i * 512, ln1_b + i * 512, y_bf);
    // FF1 (gelu) -> bf16  [grid 65x32 = 2080]
    gemm_bt<1><<<65 * 32, 256, 0, stream>>>(y_bf, w1, b1 + i * 2048, nullptr, h_bf, 512, 2048, 32);
    // FF2 + residual(y) -> s bf16  [grid 65x8 = 520]
    gemm_bt<3><<<65 * 8, 256, 0, stream>>>(h_bf, w2, b2 + i * 512, y_bf, t0bf, 2048, 512, 8);
    ln_k<<<MROWS, 128, 0, stream>>>(t0bf, ln2_g + i * 512, ln2_b + i * 512, x_bf);
  }
  final_head_k<<<MROWS, 128, 0, stream>>>(x_bf, normf_g, normf_b, cond_emb, cond,
                                          outg_W, outg_b, outl_W, outl_b, (float*)d_out);
}